// Round 9
// baseline (300.425 us; speedup 1.0000x reference)
//
#include <hip/hip_runtime.h>

// B=8, T=1024, D=1024, H=16, Dh=64. x/w/b fp32 (probe-verified; dual path
// kept), lengths int32, output dtype follows probe flag.
//
// R15: FOUR gemm structures (R6/R9/R12/R14) all pinned at ~93-98us / 550TF,
// MfmaUtil ~22% -> the 128x128 4-wave family is structurally capped at this
// shape; micro-schedule (counted vmcnt, unroll) is not the lever. Port the
// 256x256 8-phase mechanism (T3+T4, m196/m198: +28-41% without swizzle) for
// gemm_qkv: 512 thr / 8 waves (2Mx4N), BK=64, 128KB dbuf LDS, 64 MFMA per
// barrier pair, half-tile staging spread across phases, vmcnt(4) at tile
// top (never 0 mid-loop), sched_barrier fences, setprio (T5 pays on
// phase-split). attn reverted to R8-exact (R14's 3-buf cost ~8us);
// gemm_out keeps R14 core (attribution).

typedef __attribute__((ext_vector_type(8))) short bf16x8;
typedef __attribute__((ext_vector_type(4))) float f32x4;

__device__ inline short f2b(float f) {
  unsigned u = __float_as_uint(f);
  unsigned r = (u + 0x7fff + ((u >> 16) & 1)) >> 16;
  return (short)r;
}
__device__ inline float b2f(short s) {
  return __uint_as_float(((unsigned)(unsigned short)s) << 16);
}

__device__ inline bf16x8 ld8(const char* p, int isf32) {
  if (isf32) {
    const float* f = (const float*)p;
    bf16x8 r;
#pragma unroll
    for (int j = 0; j < 8; j++) r[j] = f2b(f[j]);
    return r;
  }
  return *(const bf16x8*)p;
}

__device__ inline float ldbias(const char* b, int n, int isf32) {
  return isf32 ? ((const float*)b)[n] : b2f(((const short*)b)[n]);
}

__device__ inline void gl_lds16(const short* g, short* l) {
  __builtin_amdgcn_global_load_lds(
      (const __attribute__((address_space(1))) void*)g,
      (__attribute__((address_space(3))) void*)l, 16, 0, 0);
}

// ---------------- dtype probe (1 block x 64) --------------------------------
__global__ void probe_k(const short* __restrict__ xs, int* __restrict__ flag) {
  int lane = threadIdx.x & 63;
  int cnt = 0;
  for (int i = lane; i < 1024; i += 64) {
    int e = (xs[2 * i] >> 7) & 0xFF;
    cnt += (e >= 0x90) ? 1 : 0;
  }
#pragma unroll
  for (int o = 1; o < 64; o <<= 1) cnt += __shfl_xor(cnt, o);
  if (lane == 0) *flag = (cnt > 100) ? 1 : 0;
}

// ---------------- x -> bf16 -------------------------------------------------
__global__ __launch_bounds__(256) void cvt_x_k(const char* __restrict__ x,
                                               short* __restrict__ xb,
                                               const int* __restrict__ flag,
                                               int b_base) {
  int isf32 = *flag;
  size_t esz = isf32 ? 4 : 2;
  size_t i = ((size_t)blockIdx.x * 256 + threadIdx.x) * 8;
  size_t g = (size_t)b_base * 1024 * 1024 + i;
  *(bf16x8*)(xb + i) = ld8(x + g * esz, isf32);
}

// ---------------- transpose out[c][r] = in[r][c] ----------------------------
__global__ __launch_bounds__(256) void transpose_k(
    const char* __restrict__ in, short* __restrict__ out, int R, int C,
    const int* __restrict__ flag) {
  __shared__ __align__(16) short tile[64][80];
  int isf32 = *flag;
  size_t esz = isf32 ? 4 : 2;
  int t = threadIdx.x;
  int r0 = blockIdx.y * 64, c0 = blockIdx.x * 64;
#pragma unroll
  for (int i = 0; i < 2; i++) {
    int s = i * 256 + t;
    int rr = s >> 3, cc = (s & 7) * 8;
    *(bf16x8*)&tile[rr][cc] =
        ld8(in + ((size_t)(r0 + rr) * C + c0 + cc) * esz, isf32);
  }
  __syncthreads();
#pragma unroll
  for (int i = 0; i < 2; i++) {
    int s = i * 256 + t;
    int cc2 = s >> 3, rr2 = (s & 7) * 8;
    bf16x8 v;
#pragma unroll
    for (int j = 0; j < 8; j++) v[j] = tile[rr2 + j][cc2];
    *(bf16x8*)(out + (size_t)(c0 + cc2) * R + r0 + rr2) = v;
  }
}

// ============ 256x256 8-phase GEMM1: C[256x256] = A @ wT^T, K=1024 ==========
// 512 threads, 8 waves (2M x 4N), per-wave 128x64 out (acc[8][4]).
// LDS: 2 slots x (A[256][64] + B[256][64]) bf16 = 128 KB.
// Per K-tile: [schedbar; barrier A (WAR); stage half#0,#1 of kt+1;
// vmcnt(4); schedbar; barrier B (publish kt); 4 phases {ds_read A-quad,
// (p0:stage#2)(p1:stage#3), setprio, 16 MFMA, setprio}]. B frags read once.
__global__ __launch_bounds__(512, 2) void gemm_qkv256_k(
    const short* __restrict__ xbf, const short* __restrict__ wT,
    const char* __restrict__ bias, short* __restrict__ Qb,
    short* __restrict__ Kb, short* __restrict__ VTb,
    const int* __restrict__ flag) {
  __shared__ __align__(16) short Ls[2][2][16384];  // [slot][A/B][row*64+k]
  int t = threadIdx.x;
  int lane = t & 63, wave = t >> 6, quad = lane >> 4, col = lane & 15;
  int wm = (wave >> 2) * 128, wn = (wave & 3) * 64;
  int m0 = blockIdx.y * 256, n0 = blockIdx.x * 256;
  const short* Ab = xbf + (size_t)m0 * 1024;
  const short* Bb = wT + (size_t)n0 * 1024;
  int srow = t >> 3;      // 0..63
  int sk = (t & 7) * 8;   // k offset (shorts)

  // stage half-tile h of K-tile kt into slot: h0=A rows0-127, h1=A 128-255,
  // h2=B 0-127, h3=B 128-255. Per-thread LDS dest is linear (t*8 within
  // each 64-row chunk) -> valid for global_load_lds.
  auto stageH = [&](int slot, int kt, int h) {
    const short* src = (h < 2) ? Ab : Bb;
    short* dst = &Ls[slot][h >> 1][0] + (h & 1) * 128 * 64;
    int kc = kt * 64 + sk;
    gl_lds16(src + (size_t)((h & 1) * 128 + srow) * 1024 + kc,
             dst + srow * 64 + sk);
    gl_lds16(src + (size_t)((h & 1) * 128 + 64 + srow) * 1024 + kc,
             dst + (64 + srow) * 64 + sk);
  };

  f32x4 acc[8][4];
#pragma unroll
  for (int i = 0; i < 8; i++)
#pragma unroll
    for (int j = 0; j < 4; j++) acc[i][j] = f32x4{0.f, 0.f, 0.f, 0.f};

  // prologue: tile 0 fully staged into slot 0 (8 loads/thread)
  stageH(0, 0, 0);
  stageH(0, 0, 1);
  stageH(0, 0, 2);
  stageH(0, 0, 3);

  for (int kt = 0; kt < 16; kt++) {
    int cs = kt & 1, ns = cs ^ 1;
    __builtin_amdgcn_sched_barrier(0);
    __builtin_amdgcn_s_barrier();  // A: prior readers of slot ns are done
    if (kt < 15) {
      stageH(ns, kt + 1, 0);
      stageH(ns, kt + 1, 1);
      asm volatile("s_waitcnt vmcnt(4)" ::: "memory");  // retire tile kt
    } else {
      asm volatile("s_waitcnt vmcnt(0)" ::: "memory");
    }
    __builtin_amdgcn_sched_barrier(0);
    __builtin_amdgcn_s_barrier();  // B: tile kt visible to all waves
    __builtin_amdgcn_sched_barrier(0);

    const short* As = &Ls[cs][0][0];
    const short* Bs = &Ls[cs][1][0];
    bf16x8 bfr[4][2];
#pragma unroll
    for (int j = 0; j < 4; j++)
#pragma unroll
      for (int hf = 0; hf < 2; hf++)
        bfr[j][hf] = *(const bf16x8*)(Bs + (wn + j * 16 + col) * 64 + hf * 32 +
                                      quad * 8);
#pragma unroll
    for (int p = 0; p < 4; p++) {
      bf16x8 af[2][2];
#pragma unroll
      for (int ii = 0; ii < 2; ii++)
#pragma unroll
        for (int hf = 0; hf < 2; hf++)
          af[ii][hf] = *(const bf16x8*)(As + (wm + (p * 2 + ii) * 16 + col) *
                                                 64 +
                                        hf * 32 + quad * 8);
      if (kt < 15 && p == 0) stageH(ns, kt + 1, 2);
      if (kt < 15 && p == 1) stageH(ns, kt + 1, 3);
      __builtin_amdgcn_s_setprio(1);
#pragma unroll
      for (int ii = 0; ii < 2; ii++)
#pragma unroll
        for (int j = 0; j < 4; j++)
#pragma unroll
          for (int hf = 0; hf < 2; hf++)
            acc[p * 2 + ii][j] = __builtin_amdgcn_mfma_f32_16x16x32_bf16(
                af[ii][hf], bfr[j][hf], acc[p * 2 + ii][j], 0, 0, 0);
      __builtin_amdgcn_s_setprio(0);
    }
  }

  int isf32 = *flag;
#pragma unroll
  for (int j = 0; j < 4; j++) {
    int n = n0 + wn + j * 16 + col;
    float bv = ldbias(bias, n, isf32);
    int qi = n >> 10, d = n & 1023, h = d >> 6, dh = d & 63;
#pragma unroll
    for (int i = 0; i < 8; i++) {
#pragma unroll
      for (int r = 0; r < 4; r++) {
        int m = m0 + wm + i * 16 + quad * 4 + r;
        int bl = m >> 10, tp = m & 1023;
        size_t bh = (size_t)bl * 16 + h;
        float val = acc[i][j][r] + bv;
        if (qi == 0)
          Qb[(bh * 1024 + tp) * 64 + dh] = f2b(val * 0.125f);
        else if (qi == 1)
          Kb[(bh * 1024 + tp) * 64 + dh] = f2b(val);
        else
          VTb[(bh * 64 + dh) * 1024 + tp] = f2b(val);
      }
    }
  }
}

// ---------------- GEMM core (R14, used by gemm_out): 128x128, K=1024 --------
template <int CUR, int MODE>
__device__ __forceinline__ void gstep(const short* __restrict__ Ab,
                                      const short* __restrict__ Bb, short* Ls,
                                      int ktn, int t, int srow, int lk, int wm,
                                      int wn, int col, int quad,
                                      f32x4 (&acc)[4][4]) {
  if (MODE == 0) {
    constexpr int SB = (CUR + 2) % 3;
    short* Ad = Ls + SB * 8192;
    short* Bd = Ad + 4096;
    gl_lds16(Ab + (size_t)srow * 1024 + ktn + lk, Ad + t * 8);
    gl_lds16(Ab + (size_t)(srow + 64) * 1024 + ktn + lk, Ad + 2048 + t * 8);
    gl_lds16(Bb + (size_t)srow * 1024 + ktn + lk, Bd + t * 8);
    gl_lds16(Bb + (size_t)(srow + 64) * 1024 + ktn + lk, Bd + 2048 + t * 8);
    asm volatile("s_waitcnt vmcnt(8)" ::: "memory");
  } else if (MODE == 1) {
    asm volatile("s_waitcnt vmcnt(4)" ::: "memory");
  } else {
    asm volatile("s_waitcnt vmcnt(0)" ::: "memory");
  }
  __builtin_amdgcn_sched_barrier(0);
  __builtin_amdgcn_s_barrier();

  const short* Ac = Ls + CUR * 8192;
  const short* Bc = Ac + 4096;
  bf16x8 af[4], bfr[4];
#pragma unroll
  for (int i = 0; i < 4; i++)
    af[i] = *(const bf16x8*)(Ac + (wm + i * 16 + col) * 32 + quad * 8);
#pragma unroll
  for (int i = 0; i < 4; i++)
    bfr[i] = *(const bf16x8*)(Bc + (wn + i * 16 + col) * 32 + quad * 8);
  __builtin_amdgcn_s_setprio(1);
#pragma unroll
  for (int i = 0; i < 4; i++)
#pragma unroll
    for (int j = 0; j < 4; j++)
      acc[i][j] = __builtin_amdgcn_mfma_f32_16x16x32_bf16(af[i], bfr[j],
                                                          acc[i][j], 0, 0, 0);
  __builtin_amdgcn_s_setprio(0);
  __builtin_amdgcn_s_barrier();

  // next iter restages CUR
}

__device__ inline void gemm_core(const short* __restrict__ A,
                                 const short* __restrict__ Bt, short* Ls,
                                 int m0, int n0, f32x4 (&acc)[4][4]) {
  int t = threadIdx.x;
  int lane = t & 63, wave = t >> 6, quad = lane >> 4, col = lane & 15;
  int wm = (wave >> 1) * 64, wn = (wave & 1) * 64;
  const short* Ab = A + (size_t)m0 * 1024;
  const short* Bb = Bt + (size_t)n0 * 1024;
  int srow = t >> 2, lk = (t & 3) * 8;

  gl_lds16(Ab + (size_t)srow * 1024 + lk, Ls + t * 8);
  gl_lds16(Ab + (size_t)(srow + 64) * 1024 + lk, Ls + 2048 + t * 8);
  gl_lds16(Bb + (size_t)srow * 1024 + lk, Ls + 4096 + t * 8);
  gl_lds16(Bb + (size_t)(srow + 64) * 1024 + lk, Ls + 4096 + 2048 + t * 8);
  gl_lds16(Ab + (size_t)srow * 1024 + 32 + lk, Ls + 8192 + t * 8);
  gl_lds16(Ab + (size_t)(srow + 64) * 1024 + 32 + lk, Ls + 8192 + 2048 + t * 8);
  gl_lds16(Bb + (size_t)srow * 1024 + 32 + lk, Ls + 8192 + 4096 + t * 8);
  gl_lds16(Bb + (size_t)(srow + 64) * 1024 + 32 + lk,
           Ls + 8192 + 4096 + 2048 + t * 8);

  for (int g = 0; g < 10; g++) {
    int kb = g * 96;
    gstep<0, 0>(Ab, Bb, Ls, kb + 64, t, srow, lk, wm, wn, col, quad, acc);
    gstep<1, 0>(Ab, Bb, Ls, kb + 96, t, srow, lk, wm, wn, col, quad, acc);
    gstep<2, 0>(Ab, Bb, Ls, kb + 128, t, srow, lk, wm, wn, col, quad, acc);
  }
  gstep<0, 1>(Ab, Bb, Ls, 0, t, srow, lk, wm, wn, col, quad, acc);
  gstep<1, 2>(Ab, Bb, Ls, 0, t, srow, lk, wm, wn, col, quad, acc);
}

// attention. Grid (8, nb*16), 4 waves; each wave owns 32 q-rows (2 q-tiles).
// R8-exact (measured-good): LDS-staged K/V, distance-1 prefetch dbuf, one
// __syncthreads per k-tile; wave-private P round-trip; early-exit.
__global__ __launch_bounds__(256, 4) void attn_k(
    const short* __restrict__ Qb, const short* __restrict__ Kb,
    const short* __restrict__ VTb, const int* __restrict__ lengths,
    short* __restrict__ Ob, int b_base) {
  __shared__ __align__(16) short Ks[2][2][64 * 32];  // [buf][half][key][d]
  __shared__ __align__(16) short Vs[2][2][64 * 32];  // [buf][half][dh][k]
  __shared__ __align__(16) short Pl[4 * 32 * 72];
  int t = threadIdx.x, wave = t >> 6, lane = t & 63, quad = lane >> 4,
      col = lane & 15;
  int bh = blockIdx.y, bl = bh >> 4, h = bh & 15;
  int len = lengths[b_base + bl];
  int qblk = blockIdx.x * 128;
  if (qblk >= len) {
    bf16x8 z;
#pragma unroll
    for (int j = 0; j < 8; j++) z[j] = 0;
    int rr = t >> 1, cc = (t & 1) * 32;
    short* dst = Ob + ((size_t)bl * 1024 + qblk + rr) * 1024 + h * 64 + cc;
#pragma unroll
    for (int j = 0; j < 4; j++) *(bf16x8*)(dst + j * 8) = z;
    return;
  }
  int qb0 = qblk + wave * 16;  // qt adds +64
  const short* Q = Qb + (size_t)bh * 1024 * 64;
  const short* K = Kb + (size_t)bh * 1024 * 64;
  const short* VT = VTb + (size_t)bh * 64 * 1024;
  short* myP = Pl + wave * 32 * 72;

  int srow = t >> 2, skk = (t & 3) * 8;

  bf16x8 qf[2][2];
#pragma unroll
  for (int qt = 0; qt < 2; qt++) {
    qf[qt][0] = *(const bf16x8*)(Q + (qb0 + qt * 64 + col) * 64 + quad * 8);
    qf[qt][1] =
        *(const bf16x8*)(Q + (qb0 + qt * 64 + col) * 64 + 32 + quad * 8);
  }

  f32x4 oacc[2][4];
  float suml[2][4];
#pragma unroll
  for (int qt = 0; qt < 2; qt++)
#pragma unroll
    for (int i = 0; i < 4; i++) {
      oacc[qt][i] = f32x4{0.f, 0.f, 0.f, 0.f};
      suml[qt][i] = 0.f;
    }

  int klim = ((len + 63) >> 6) << 6;  // block-uniform, <= 1024

  gl_lds16(K + (size_t)srow * 64 + skk, Ks[0][0] + t * 8);
  gl_lds16(K + (size_t)srow * 64 + 32 + skk, Ks[0][1] + t * 8);
  gl_lds16(VT + (size_t)srow * 1024 + skk, Vs[0][0] + t * 8);
  gl_lds16(VT + (size_t)srow * 1024 + 32 + skk, Vs[0][1] + t * 8);
  __syncthreads();

  for (int k0 = 0; k0 < klim; k0 += 64) {
    int cur = (k0 >> 6) & 1;
    if (k0 + 64 < klim) {
      int nx = cur ^ 1, kn = k0 + 64;
      gl_lds16(K + (size_t)(kn + srow) * 64 + skk, Ks[nx][0] + t * 8);
      gl_lds16(K + (size_t)(kn + srow) * 64 + 32 + skk, Ks[nx][1] + t * 8);
      gl_lds16(VT + (size_t)srow * 1024 + kn + skk, Vs[nx][0] + t * 8);
      gl_lds16(VT + (size_t)srow * 1024 + kn + 32 + skk, Vs[nx][1] + t * 8);
    }

#pragma unroll
    for (int qt = 0; qt < 2; qt++) {
      f32x4 s[4];
#pragma unroll
      for (int ks = 0; ks < 4; ks++) s[ks] = f32x4{0.f, 0.f, 0.f, 0.f};
      __builtin_amdgcn_s_setprio(1);
#pragma unroll
      for (int ks = 0; ks < 4; ks++) {
        bf16x8 klo =
            *(const bf16x8*)(Ks[cur][0] + (ks * 16 + col) * 32 + quad * 8);
        bf16x8 khi =
            *(const bf16x8*)(Ks[cur][1] + (ks * 16 + col) * 32 + quad * 8);
        s[ks] = __builtin_amdgcn_mfma_f32_16x16x32_bf16(qf[qt][0], klo, s[ks],
                                                        0, 0, 0);
        s[ks] = __builtin_amdgcn_mfma_f32_16x16x32_bf16(qf[qt][1], khi, s[ks],
                                                        0, 0, 0);
      }
      __builtin_amdgcn_s_setprio(0);
#pragma unroll
      for (int ks = 0; ks < 4; ks++) {
#pragma unroll
        for (int r = 0; r < 4; r++) {
          float e = (k0 + ks * 16 + col < len) ? __expf(s[ks][r]) : 0.f;
          suml[qt][r] += e;
          myP[(qt * 16 + quad * 4 + r) * 72 + ks * 16 + col] = f2b(e);
        }
      }
    }
#pragma unroll
    for (int qt = 0; qt < 2; qt++) {
      bf16x8 pf0 = *(const bf16x8*)(myP + (qt * 16 + col) * 72 + quad * 8);
      bf16x8 pf1 = *(const bf16x8*)(myP + (qt * 16 + col) * 72 + 32 + quad * 8);
      __builtin_amdgcn_s_setprio(1);
#pragma unroll
      for (int nt = 0; nt < 4; nt++) {
        bf16x8 v0 =
            *(const bf16x8*)(Vs[cur][0] + (nt * 16 + col) * 32 + quad * 8);
        bf16x8 v1 =
            *(const bf16x8*)(Vs[cur][1] + (nt * 16 + col) * 32 + quad * 8);
        oacc[qt][nt] = __builtin_amdgcn_mfma_f32_16x16x32_bf16(
            pf0, v0, oacc[qt][nt], 0, 0, 0);
        oacc[qt][nt] = __builtin_amdgcn_mfma_f32_16x16x32_bf16(
            pf1, v1, oacc[qt][nt], 0, 0, 0);
      }
      __builtin_amdgcn_s_setprio(0);
    }
    __syncthreads();
  }
#pragma unroll
  for (int qt = 0; qt < 2; qt++)
#pragma unroll
    for (int r = 0; r < 4; r++) {
      suml[qt][r] += __shfl_xor(suml[qt][r], 1);
      suml[qt][r] += __shfl_xor(suml[qt][r], 2);
      suml[qt][r] += __shfl_xor(suml[qt][r], 4);
      suml[qt][r] += __shfl_xor(suml[qt][r], 8);
    }
#pragma unroll
  for (int qt = 0; qt < 2; qt++)
#pragma unroll
    for (int nt = 0; nt < 4; nt++)
#pragma unroll
      for (int r = 0; r < 4; r++) {
        int q = qb0 + qt * 64 + quad * 4 + r;
        float v = (q < len) ? oacc[qt][nt][r] / suml[qt][r] : 0.f;
        Ob[((size_t)bl * 1024 + q) * 1024 + h * 64 + nt * 16 + col] = f2b(v);
      }
}

// GEMM2. Grid (8, nb*8). Output dtype follows flag.
__global__ __launch_bounds__(256, 3) void gemm_out_k(
    const short* __restrict__ O, const short* __restrict__ wT,
    const char* __restrict__ bias, char* __restrict__ out,
    const int* __restrict__ flag, int m_base) {
  __shared__ __align__(16) short Ls[3 * 8192];
  int isf32 = *flag;
  f32x4 acc[4][4];
#pragma unroll
  for (int i = 0; i < 4; i++)
#pragma unroll
    for (int j = 0; j < 4; j++) acc[i][j] = f32x4{0.f, 0.f, 0.f, 0.f};
  int m0 = blockIdx.y * 128, n0 = blockIdx.x * 128;
  gemm_core(O, wT, Ls, m0, n0, acc);
  int t = threadIdx.x, wave = t >> 6, lane = t & 63, quad = lane >> 4,
      col = lane & 15;
  int wm = (wave >> 1) * 64, wn = (wave & 1) * 64;
#pragma unroll
  for (int j = 0; j < 4; j++) {
    int n = n0 + wn + j * 16 + col;
    float bv = ldbias(bias, n, isf32);
#pragma unroll
    for (int i = 0; i < 4; i++) {
#pragma unroll
      for (int r = 0; r < 4; r++) {
        int m = m0 + wm + i * 16 + quad * 4 + r;
        size_t idx = (size_t)(m_base + m) * 1024 + n;
        float val = acc[i][j][r] + bv;
        if (isf32)
          ((float*)out)[idx] = val;
        else
          ((short*)out)[idx] = f2b(val);
      }
    }
  }
}

extern "C" void kernel_launch(void* const* d_in, const int* in_sizes, int n_in,
                              void* d_out, int out_size, void* d_ws,
                              size_t ws_size, hipStream_t stream) {
  const char* x = (const char*)d_in[0];
  const int* lengths = (const int*)d_in[1];
  const char* w_qkv = (const char*)d_in[2];
  const char* b_qkv = (const char*)d_in[3];
  const char* w_o = (const char*)d_in[4];
  const char* b_o = (const char*)d_in[5];
  char* out = (char*)d_out;

  char* ws = (char*)d_ws;
  int* flag = (int*)ws;        ws += 256;
  short* wT_qkv = (short*)ws;  ws += (size_t)3072 * 1024 * 2;  // 6.3 MB
  short* wT_o = (short*)ws;    ws += (size_t)1024 * 1024 * 2;  // 2.1 MB
  char* dynbase = ws;
  size_t fixed = (size_t)(dynbase - (char*)d_ws);
  size_t per_batch = (size_t)16 * 1024 * 64 * 2;  // 2.10 MB / tensor
  size_t need_full = fixed + 4 * 8 * per_batch;   // ~75.8 MB (fits, R3-R5)
  int nb = (ws_size >= need_full) ? 8 : 1;

  // xbf aliases Ob: x consumed by GEMM1 before attn writes Ob.
  short* xbf_Ob = (short*)dynbase;
  short* Qb = xbf_Ob + (size_t)nb * 16 * 1024 * 64;
  short* Kb = Qb + (size_t)nb * 16 * 1024 * 64;
  short* VTb = Kb + (size_t)nb * 16 * 1024 * 64;

  dim3 blk(256);
  probe_k<<<1, 64, 0, stream>>>((const short*)x, flag);
  transpose_k<<<dim3(48, 16), blk, 0, stream>>>(w_qkv, wT_qkv, 1024, 3072, flag);
  transpose_k<<<dim3(16, 16), blk, 0, stream>>>(w_o, wT_o, 1024, 1024, flag);
  for (int b0 = 0; b0 < 8; b0 += nb) {
    cvt_x_k<<<dim3(nb * 512), blk, 0, stream>>>(x, xbf_Ob, flag, b0);
    gemm_qkv256_k<<<dim3(12, nb * 4), dim3(512), 0, stream>>>(
        xbf_Ob, wT_qkv, b_qkv, Qb, Kb, VTb, flag);
    attn_k<<<dim3(8, nb * 16), blk, 0, stream>>>(Qb, Kb, VTb, lengths, xbf_Ob,
                                                 b0);
    gemm_out_k<<<dim3(8, nb * 8), blk, 0, stream>>>(xbf_Ob, wT_o, b_o, out,
                                                    flag, b0 * 1024);
  }
}

// Round 10
// 285.893 us; speedup vs baseline: 1.0508x; 1.0508x over previous
//
#include <hip/hip_runtime.h>

// B=8, T=1024, D=1024, H=16, Dh=64. x/w/b fp32 (probe-verified; dual path
// kept), lengths int32, output dtype follows probe flag.
//
// R16 = R15 + correct T2 swizzle on gemm_qkv256. R15 (122us, MfmaUtil 16.9%,
// BANK_CONFLICT 14.16M = 12 cyc/read) proved the [256][64] tile's 128B row
// stride is a 16-way conflict on every ds_read_b128 (m201's exact case) and
// that LDS serialization, not barriers/VALU, capped ALL prior gemm variants
// (R6/R9/R12/R14 shared one read layout -> constant 6.29M; R10's "swizzle"
// was bank-preserving across the wave -> provable no-op). Fix (rule #21
// both-sides): gl_lds dest linear; GLOBAL source k-slot ^= row&7; read slot
// = (hf*4+quad) ^ (col&7) (per-lane constant; row&7==col&7 for all frag
// rows). Each 8-lane phase now covers all 8 bank-quads -> <=2-way (free).
// attn = R8-exact; gemm_out = R14 core.

typedef __attribute__((ext_vector_type(8))) short bf16x8;
typedef __attribute__((ext_vector_type(4))) float f32x4;

__device__ inline short f2b(float f) {
  unsigned u = __float_as_uint(f);
  unsigned r = (u + 0x7fff + ((u >> 16) & 1)) >> 16;
  return (short)r;
}
__device__ inline float b2f(short s) {
  return __uint_as_float(((unsigned)(unsigned short)s) << 16);
}

__device__ inline bf16x8 ld8(const char* p, int isf32) {
  if (isf32) {
    const float* f = (const float*)p;
    bf16x8 r;
#pragma unroll
    for (int j = 0; j < 8; j++) r[j] = f2b(f[j]);
    return r;
  }
  return *(const bf16x8*)p;
}

__device__ inline float ldbias(const char* b, int n, int isf32) {
  return isf32 ? ((const float*)b)[n] : b2f(((const short*)b)[n]);
}

__device__ inline void gl_lds16(const short* g, short* l) {
  __builtin_amdgcn_global_load_lds(
      (const __attribute__((address_space(1))) void*)g,
      (__attribute__((address_space(3))) void*)l, 16, 0, 0);
}

// ---------------- dtype probe (1 block x 64) --------------------------------
__global__ void probe_k(const short* __restrict__ xs, int* __restrict__ flag) {
  int lane = threadIdx.x & 63;
  int cnt = 0;
  for (int i = lane; i < 1024; i += 64) {
    int e = (xs[2 * i] >> 7) & 0xFF;
    cnt += (e >= 0x90) ? 1 : 0;
  }
#pragma unroll
  for (int o = 1; o < 64; o <<= 1) cnt += __shfl_xor(cnt, o);
  if (lane == 0) *flag = (cnt > 100) ? 1 : 0;
}

// ---------------- x -> bf16 -------------------------------------------------
__global__ __launch_bounds__(256) void cvt_x_k(const char* __restrict__ x,
                                               short* __restrict__ xb,
                                               const int* __restrict__ flag,
                                               int b_base) {
  int isf32 = *flag;
  size_t esz = isf32 ? 4 : 2;
  size_t i = ((size_t)blockIdx.x * 256 + threadIdx.x) * 8;
  size_t g = (size_t)b_base * 1024 * 1024 + i;
  *(bf16x8*)(xb + i) = ld8(x + g * esz, isf32);
}

// ---------------- transpose out[c][r] = in[r][c] ----------------------------
__global__ __launch_bounds__(256) void transpose_k(
    const char* __restrict__ in, short* __restrict__ out, int R, int C,
    const int* __restrict__ flag) {
  __shared__ __align__(16) short tile[64][80];
  int isf32 = *flag;
  size_t esz = isf32 ? 4 : 2;
  int t = threadIdx.x;
  int r0 = blockIdx.y * 64, c0 = blockIdx.x * 64;
#pragma unroll
  for (int i = 0; i < 2; i++) {
    int s = i * 256 + t;
    int rr = s >> 3, cc = (s & 7) * 8;
    *(bf16x8*)&tile[rr][cc] =
        ld8(in + ((size_t)(r0 + rr) * C + c0 + cc) * esz, isf32);
  }
  __syncthreads();
#pragma unroll
  for (int i = 0; i < 2; i++) {
    int s = i * 256 + t;
    int cc2 = s >> 3, rr2 = (s & 7) * 8;
    bf16x8 v;
#pragma unroll
    for (int j = 0; j < 8; j++) v[j] = tile[rr2 + j][cc2];
    *(bf16x8*)(out + (size_t)(c0 + cc2) * R + r0 + rr2) = v;
  }
}

// ============ 256x256 8-phase GEMM1: C[256x256] = A @ wT^T, K=1024 ==========
// 512 threads, 8 waves (2M x 4N), per-wave 128x64 out (acc[8][4]).
// LDS: 2 slots x (A[256][64] + B[256][64]) bf16 = 128 KB.
// T2 swizzle: LDS(row, slot) holds global(row, slot ^ (row&7)); slot = 16B
// unit (8 per 128B row). Store side swizzles the GLOBAL src; dest linear.
__global__ __launch_bounds__(512, 2) void gemm_qkv256_k(
    const short* __restrict__ xbf, const short* __restrict__ wT,
    const char* __restrict__ bias, short* __restrict__ Qb,
    short* __restrict__ Kb, short* __restrict__ VTb,
    const int* __restrict__ flag) {
  __shared__ __align__(16) short Ls[2][2][16384];  // [slot][A/B][row*64+k]
  int t = threadIdx.x;
  int lane = t & 63, wave = t >> 6, quad = lane >> 4, col = lane & 15;
  int wm = (wave >> 2) * 128, wn = (wave & 3) * 64;
  int m0 = blockIdx.y * 256, n0 = blockIdx.x * 256;
  const short* Ab = xbf + (size_t)m0 * 1024;
  const short* Bb = wT + (size_t)n0 * 1024;
  int srow = t >> 3;                          // 0..63
  int skl = (t & 7) * 8;                      // linear LDS k-slot (shorts)
  int skg = (((t & 7) ^ (srow & 7))) * 8;     // swizzled GLOBAL k-slot
  int cx7 = col & 7;
  int rs0 = (quad ^ cx7) * 8;        // read slot, k-half 0
  int rs1 = ((4 + quad) ^ cx7) * 8;  // read slot, k-half 1

  // stage half-tile h of K-tile kt into slot: h0=A rows0-127, h1=A 128-255,
  // h2=B 0-127, h3=B 128-255. LDS dest linear (t*8 per 64-row chunk);
  // global source k pre-swizzled. (row&7 == srow&7 for both rows: 64,128=0 mod 8.)
  auto stageH = [&](int slot, int kt, int h) {
    const short* src = (h < 2) ? Ab : Bb;
    short* dst = &Ls[slot][h >> 1][0] + (h & 1) * 128 * 64;
    int kc = kt * 64 + skg;
    gl_lds16(src + (size_t)((h & 1) * 128 + srow) * 1024 + kc,
             dst + srow * 64 + skl);
    gl_lds16(src + (size_t)((h & 1) * 128 + 64 + srow) * 1024 + kc,
             dst + (64 + srow) * 64 + skl);
  };

  f32x4 acc[8][4];
#pragma unroll
  for (int i = 0; i < 8; i++)
#pragma unroll
    for (int j = 0; j < 4; j++) acc[i][j] = f32x4{0.f, 0.f, 0.f, 0.f};

  // prologue: tile 0 fully staged into slot 0 (8 loads/thread)
  stageH(0, 0, 0);
  stageH(0, 0, 1);
  stageH(0, 0, 2);
  stageH(0, 0, 3);

  for (int kt = 0; kt < 16; kt++) {
    int cs = kt & 1, ns = cs ^ 1;
    __builtin_amdgcn_sched_barrier(0);
    __builtin_amdgcn_s_barrier();  // A: prior readers of slot ns are done
    if (kt < 15) {
      stageH(ns, kt + 1, 0);
      stageH(ns, kt + 1, 1);
      asm volatile("s_waitcnt vmcnt(4)" ::: "memory");  // retire tile kt
    } else {
      asm volatile("s_waitcnt vmcnt(0)" ::: "memory");
    }
    __builtin_amdgcn_sched_barrier(0);
    __builtin_amdgcn_s_barrier();  // B: tile kt visible to all waves
    __builtin_amdgcn_sched_barrier(0);

    const short* As = &Ls[cs][0][0];
    const short* Bs = &Ls[cs][1][0];
    bf16x8 bfr[4][2];
#pragma unroll
    for (int j = 0; j < 4; j++) {
      const short* bp = Bs + (wn + j * 16 + col) * 64;
      bfr[j][0] = *(const bf16x8*)(bp + rs0);
      bfr[j][1] = *(const bf16x8*)(bp + rs1);
    }
#pragma unroll
    for (int p = 0; p < 4; p++) {
      bf16x8 af[2][2];
#pragma unroll
      for (int ii = 0; ii < 2; ii++) {
        const short* ap = As + (wm + (p * 2 + ii) * 16 + col) * 64;
        af[ii][0] = *(const bf16x8*)(ap + rs0);
        af[ii][1] = *(const bf16x8*)(ap + rs1);
      }
      if (kt < 15 && p == 0) stageH(ns, kt + 1, 2);
      if (kt < 15 && p == 1) stageH(ns, kt + 1, 3);
      __builtin_amdgcn_s_setprio(1);
#pragma unroll
      for (int ii = 0; ii < 2; ii++)
#pragma unroll
        for (int j = 0; j < 4; j++)
#pragma unroll
          for (int hf = 0; hf < 2; hf++)
            acc[p * 2 + ii][j] = __builtin_amdgcn_mfma_f32_16x16x32_bf16(
                af[ii][hf], bfr[j][hf], acc[p * 2 + ii][j], 0, 0, 0);
      __builtin_amdgcn_s_setprio(0);
    }
  }

  int isf32 = *flag;
#pragma unroll
  for (int j = 0; j < 4; j++) {
    int n = n0 + wn + j * 16 + col;
    float bv = ldbias(bias, n, isf32);
    int qi = n >> 10, d = n & 1023, h = d >> 6, dh = d & 63;
#pragma unroll
    for (int i = 0; i < 8; i++) {
#pragma unroll
      for (int r = 0; r < 4; r++) {
        int m = m0 + wm + i * 16 + quad * 4 + r;
        int bl = m >> 10, tp = m & 1023;
        size_t bh = (size_t)bl * 16 + h;
        float val = acc[i][j][r] + bv;
        if (qi == 0)
          Qb[(bh * 1024 + tp) * 64 + dh] = f2b(val * 0.125f);
        else if (qi == 1)
          Kb[(bh * 1024 + tp) * 64 + dh] = f2b(val);
        else
          VTb[(bh * 64 + dh) * 1024 + tp] = f2b(val);
      }
    }
  }
}

// ---------------- GEMM core (R14, used by gemm_out): 128x128, K=1024 --------
template <int CUR, int MODE>
__device__ __forceinline__ void gstep(const short* __restrict__ Ab,
                                      const short* __restrict__ Bb, short* Ls,
                                      int ktn, int t, int srow, int lk, int wm,
                                      int wn, int col, int quad,
                                      f32x4 (&acc)[4][4]) {
  if (MODE == 0) {
    constexpr int SB = (CUR + 2) % 3;
    short* Ad = Ls + SB * 8192;
    short* Bd = Ad + 4096;
    gl_lds16(Ab + (size_t)srow * 1024 + ktn + lk, Ad + t * 8);
    gl_lds16(Ab + (size_t)(srow + 64) * 1024 + ktn + lk, Ad + 2048 + t * 8);
    gl_lds16(Bb + (size_t)srow * 1024 + ktn + lk, Bd + t * 8);
    gl_lds16(Bb + (size_t)(srow + 64) * 1024 + ktn + lk, Bd + 2048 + t * 8);
    asm volatile("s_waitcnt vmcnt(8)" ::: "memory");
  } else if (MODE == 1) {
    asm volatile("s_waitcnt vmcnt(4)" ::: "memory");
  } else {
    asm volatile("s_waitcnt vmcnt(0)" ::: "memory");
  }
  __builtin_amdgcn_sched_barrier(0);
  __builtin_amdgcn_s_barrier();

  const short* Ac = Ls + CUR * 8192;
  const short* Bc = Ac + 4096;
  bf16x8 af[4], bfr[4];
#pragma unroll
  for (int i = 0; i < 4; i++)
    af[i] = *(const bf16x8*)(Ac + (wm + i * 16 + col) * 32 + quad * 8);
#pragma unroll
  for (int i = 0; i < 4; i++)
    bfr[i] = *(const bf16x8*)(Bc + (wn + i * 16 + col) * 32 + quad * 8);
  __builtin_amdgcn_s_setprio(1);
#pragma unroll
  for (int i = 0; i < 4; i++)
#pragma unroll
    for (int j = 0; j < 4; j++)
      acc[i][j] = __builtin_amdgcn_mfma_f32_16x16x32_bf16(af[i], bfr[j],
                                                          acc[i][j], 0, 0, 0);
  __builtin_amdgcn_s_setprio(0);
  __builtin_amdgcn_s_barrier();
}

__device__ inline void gemm_core(const short* __restrict__ A,
                                 const short* __restrict__ Bt, short* Ls,
                                 int m0, int n0, f32x4 (&acc)[4][4]) {
  int t = threadIdx.x;
  int lane = t & 63, wave = t >> 6, quad = lane >> 4, col = lane & 15;
  int wm = (wave >> 1) * 64, wn = (wave & 1) * 64;
  const short* Ab = A + (size_t)m0 * 1024;
  const short* Bb = Bt + (size_t)n0 * 1024;
  int srow = t >> 2, lk = (t & 3) * 8;

  gl_lds16(Ab + (size_t)srow * 1024 + lk, Ls + t * 8);
  gl_lds16(Ab + (size_t)(srow + 64) * 1024 + lk, Ls + 2048 + t * 8);
  gl_lds16(Bb + (size_t)srow * 1024 + lk, Ls + 4096 + t * 8);
  gl_lds16(Bb + (size_t)(srow + 64) * 1024 + lk, Ls + 4096 + 2048 + t * 8);
  gl_lds16(Ab + (size_t)srow * 1024 + 32 + lk, Ls + 8192 + t * 8);
  gl_lds16(Ab + (size_t)(srow + 64) * 1024 + 32 + lk, Ls + 8192 + 2048 + t * 8);
  gl_lds16(Bb + (size_t)srow * 1024 + 32 + lk, Ls + 8192 + 4096 + t * 8);
  gl_lds16(Bb + (size_t)(srow + 64) * 1024 + 32 + lk,
           Ls + 8192 + 4096 + 2048 + t * 8);

  for (int g = 0; g < 10; g++) {
    int kb = g * 96;
    gstep<0, 0>(Ab, Bb, Ls, kb + 64, t, srow, lk, wm, wn, col, quad, acc);
    gstep<1, 0>(Ab, Bb, Ls, kb + 96, t, srow, lk, wm, wn, col, quad, acc);
    gstep<2, 0>(Ab, Bb, Ls, kb + 128, t, srow, lk, wm, wn, col, quad, acc);
  }
  gstep<0, 1>(Ab, Bb, Ls, 0, t, srow, lk, wm, wn, col, quad, acc);
  gstep<1, 2>(Ab, Bb, Ls, 0, t, srow, lk, wm, wn, col, quad, acc);
}

// attention. Grid (8, nb*16), 4 waves; each wave owns 32 q-rows (2 q-tiles).
// R8-exact (measured-good): LDS-staged K/V, distance-1 prefetch dbuf, one
// __syncthreads per k-tile; wave-private P round-trip; early-exit.
__global__ __launch_bounds__(256, 4) void attn_k(
    const short* __restrict__ Qb, const short* __restrict__ Kb,
    const short* __restrict__ VTb, const int* __restrict__ lengths,
    short* __restrict__ Ob, int b_base) {
  __shared__ __align__(16) short Ks[2][2][64 * 32];  // [buf][half][key][d]
  __shared__ __align__(16) short Vs[2][2][64 * 32];  // [buf][half][dh][k]
  __shared__ __align__(16) short Pl[4 * 32 * 72];
  int t = threadIdx.x, wave = t >> 6, lane = t & 63, quad = lane >> 4,
      col = lane & 15;
  int bh = blockIdx.y, bl = bh >> 4, h = bh & 15;
  int len = lengths[b_base + bl];
  int qblk = blockIdx.x * 128;
  if (qblk >= len) {
    bf16x8 z;
#pragma unroll
    for (int j = 0; j < 8; j++) z[j] = 0;
    int rr = t >> 1, cc = (t & 1) * 32;
    short* dst = Ob + ((size_t)bl * 1024 + qblk + rr) * 1024 + h * 64 + cc;
#pragma unroll
    for (int j = 0; j < 4; j++) *(bf16x8*)(dst + j * 8) = z;
    return;
  }
  int qb0 = qblk + wave * 16;  // qt adds +64
  const short* Q = Qb + (size_t)bh * 1024 * 64;
  const short* K = Kb + (size_t)bh * 1024 * 64;
  const short* VT = VTb + (size_t)bh * 64 * 1024;
  short* myP = Pl + wave * 32 * 72;

  int srow = t >> 2, skk = (t & 3) * 8;

  bf16x8 qf[2][2];
#pragma unroll
  for (int qt = 0; qt < 2; qt++) {
    qf[qt][0] = *(const bf16x8*)(Q + (qb0 + qt * 64 + col) * 64 + quad * 8);
    qf[qt][1] =
        *(const bf16x8*)(Q + (qb0 + qt * 64 + col) * 64 + 32 + quad * 8);
  }

  f32x4 oacc[2][4];
  float suml[2][4];
#pragma unroll
  for (int qt = 0; qt < 2; qt++)
#pragma unroll
    for (int i = 0; i < 4; i++) {
      oacc[qt][i] = f32x4{0.f, 0.f, 0.f, 0.f};
      suml[qt][i] = 0.f;
    }

  int klim = ((len + 63) >> 6) << 6;  // block-uniform, <= 1024

  gl_lds16(K + (size_t)srow * 64 + skk, Ks[0][0] + t * 8);
  gl_lds16(K + (size_t)srow * 64 + 32 + skk, Ks[0][1] + t * 8);
  gl_lds16(VT + (size_t)srow * 1024 + skk, Vs[0][0] + t * 8);
  gl_lds16(VT + (size_t)srow * 1024 + 32 + skk, Vs[0][1] + t * 8);
  __syncthreads();

  for (int k0 = 0; k0 < klim; k0 += 64) {
    int cur = (k0 >> 6) & 1;
    if (k0 + 64 < klim) {
      int nx = cur ^ 1, kn = k0 + 64;
      gl_lds16(K + (size_t)(kn + srow) * 64 + skk, Ks[nx][0] + t * 8);
      gl_lds16(K + (size_t)(kn + srow) * 64 + 32 + skk, Ks[nx][1] + t * 8);
      gl_lds16(VT + (size_t)srow * 1024 + kn + skk, Vs[nx][0] + t * 8);
      gl_lds16(VT + (size_t)srow * 1024 + kn + 32 + skk, Vs[nx][1] + t * 8);
    }

#pragma unroll
    for (int qt = 0; qt < 2; qt++) {
      f32x4 s[4];
#pragma unroll
      for (int ks = 0; ks < 4; ks++) s[ks] = f32x4{0.f, 0.f, 0.f, 0.f};
      __builtin_amdgcn_s_setprio(1);
#pragma unroll
      for (int ks = 0; ks < 4; ks++) {
        bf16x8 klo =
            *(const bf16x8*)(Ks[cur][0] + (ks * 16 + col) * 32 + quad * 8);
        bf16x8 khi =
            *(const bf16x8*)(Ks[cur][1] + (ks * 16 + col) * 32 + quad * 8);
        s[ks] = __builtin_amdgcn_mfma_f32_16x16x32_bf16(qf[qt][0], klo, s[ks],
                                                        0, 0, 0);
        s[ks] = __builtin_amdgcn_mfma_f32_16x16x32_bf16(qf[qt][1], khi, s[ks],
                                                        0, 0, 0);
      }
      __builtin_amdgcn_s_setprio(0);
#pragma unroll
      for (int ks = 0; ks < 4; ks++) {
#pragma unroll
        for (int r = 0; r < 4; r++) {
          float e = (k0 + ks * 16 + col < len) ? __expf(s[ks][r]) : 0.f;
          suml[qt][r] += e;
          myP[(qt * 16 + quad * 4 + r) * 72 + ks * 16 + col] = f2b(e);
        }
      }
    }
#pragma unroll
    for (int qt = 0; qt < 2; qt++) {
      bf16x8 pf0 = *(const bf16x8*)(myP + (qt * 16 + col) * 72 + quad * 8);
      bf16x8 pf1 = *(const bf16x8*)(myP + (qt * 16 + col) * 72 + 32 + quad * 8);
      __builtin_amdgcn_s_setprio(1);
#pragma unroll
      for (int nt = 0; nt < 4; nt++) {
        bf16x8 v0 =
            *(const bf16x8*)(Vs[cur][0] + (nt * 16 + col) * 32 + quad * 8);
        bf16x8 v1 =
            *(const bf16x8*)(Vs[cur][1] + (nt * 16 + col) * 32 + quad * 8);
        oacc[qt][nt] = __builtin_amdgcn_mfma_f32_16x16x32_bf16(
            pf0, v0, oacc[qt][nt], 0, 0, 0);
        oacc[qt][nt] = __builtin_amdgcn_mfma_f32_16x16x32_bf16(
            pf1, v1, oacc[qt][nt], 0, 0, 0);
      }
      __builtin_amdgcn_s_setprio(0);
    }
    __syncthreads();
  }
#pragma unroll
  for (int qt = 0; qt < 2; qt++)
#pragma unroll
    for (int r = 0; r < 4; r++) {
      suml[qt][r] += __shfl_xor(suml[qt][r], 1);
      suml[qt][r] += __shfl_xor(suml[qt][r], 2);
      suml[qt][r] += __shfl_xor(suml[qt][r], 4);
      suml[qt][r] += __shfl_xor(suml[qt][r], 8);
    }
#pragma unroll
  for (int qt = 0; qt < 2; qt++)
#pragma unroll
    for (int nt = 0; nt < 4; nt++)
#pragma unroll
      for (int r = 0; r < 4; r++) {
        int q = qb0 + qt * 64 + quad * 4 + r;
        float v = (q < len) ? oacc[qt][nt][r] / suml[qt][r] : 0.f;
        Ob[((size_t)bl * 1024 + q) * 1024 + h * 64 + nt * 16 + col] = f2b(v);
      }
}

// GEMM2. Grid (8, nb*8). Output dtype follows flag.
__global__ __launch_bounds__(256, 3) void gemm_out_k(
    const short* __restrict__ O, const short* __restrict__ wT,
    const char* __restrict__ bias, char* __restrict__ out,
    const int* __restrict__ flag, int m_base) {
  __shared__ __align__(16) short Ls[3 * 8192];
  int isf32 = *flag;
  f32x4 acc[4][4];
#pragma unroll
  for (int i = 0; i < 4; i++)
#pragma unroll
    for (int j = 0; j < 4; j++) acc[i][j] = f32x4{0.f, 0.f, 0.f, 0.f};
  int m0 = blockIdx.y * 128, n0 = blockIdx.x * 128;
  gemm_core(O, wT, Ls, m0, n0, acc);
  int t = threadIdx.x, wave = t >> 6, lane = t & 63, quad = lane >> 4,
      col = lane & 15;
  int wm = (wave >> 1) * 64, wn = (wave & 1) * 64;
#pragma unroll
  for (int j = 0; j < 4; j++) {
    int n = n0 + wn + j * 16 + col;
    float bv = ldbias(bias, n, isf32);
#pragma unroll
    for (int i = 0; i < 4; i++) {
#pragma unroll
      for (int r = 0; r < 4; r++) {
        int m = m0 + wm + i * 16 + quad * 4 + r;
        size_t idx = (size_t)(m_base + m) * 1024 + n;
        float val = acc[i][j][r] + bv;
        if (isf32)
          ((float*)out)[idx] = val;
        else
          ((short*)out)[idx] = f2b(val);
      }
    }
  }
}

extern "C" void kernel_launch(void* const* d_in, const int* in_sizes, int n_in,
                              void* d_out, int out_size, void* d_ws,
                              size_t ws_size, hipStream_t stream) {
  const char* x = (const char*)d_in[0];
  const int* lengths = (const int*)d_in[1];
  const char* w_qkv = (const char*)d_in[2];
  const char* b_qkv = (const char*)d_in[3];
  const char* w_o = (const char*)d_in[4];
  const char* b_o = (const char*)d_in[5];
  char* out = (char*)d_out;

  char* ws = (char*)d_ws;
  int* flag = (int*)ws;        ws += 256;
  short* wT_qkv = (short*)ws;  ws += (size_t)3072 * 1024 * 2;  // 6.3 MB
  short* wT_o = (short*)ws;    ws += (size_t)1024 * 1024 * 2;  // 2.1 MB
  char* dynbase = ws;
  size_t fixed = (size_t)(dynbase - (char*)d_ws);
  size_t per_batch = (size_t)16 * 1024 * 64 * 2;  // 2.10 MB / tensor
  size_t need_full = fixed + 4 * 8 * per_batch;   // ~75.8 MB (fits, R3-R5)
  int nb = (ws_size >= need_full) ? 8 : 1;

  // xbf aliases Ob: x consumed by GEMM1 before attn writes Ob.
  short* xbf_Ob = (short*)dynbase;
  short* Qb = xbf_Ob + (size_t)nb * 16 * 1024 * 64;
  short* Kb = Qb + (size_t)nb * 16 * 1024 * 64;
  short* VTb = Kb + (size_t)nb * 16 * 1024 * 64;

  dim3 blk(256);
  probe_k<<<1, 64, 0, stream>>>((const short*)x, flag);
  transpose_k<<<dim3(48, 16), blk, 0, stream>>>(w_qkv, wT_qkv, 1024, 3072, flag);
  transpose_k<<<dim3(16, 16), blk, 0, stream>>>(w_o, wT_o, 1024, 1024, flag);
  for (int b0 = 0; b0 < 8; b0 += nb) {
    cvt_x_k<<<dim3(nb * 512), blk, 0, stream>>>(x, xbf_Ob, flag, b0);
    gemm_qkv256_k<<<dim3(12, nb * 4), dim3(512), 0, stream>>>(
        xbf_Ob, wT_qkv, b_qkv, Qb, Kb, VTb, flag);
    attn_k<<<dim3(8, nb * 16), blk, 0, stream>>>(Qb, Kb, VTb, lengths, xbf_Ob,
                                                 b0);
    gemm_out_k<<<dim3(8, nb * 8), blk, 0, stream>>>(xbf_Ob, wT_o, b_o, out,
                                                    flag, b0 * 1024);
  }
}

// Round 11
// 280.651 us; speedup vs baseline: 1.0705x; 1.0187x over previous
//
#include <hip/hip_runtime.h>

// B=8, T=1024, D=1024, H=16, Dh=64. x/w/b fp32 (probe-verified; dual path
// kept), lengths int32, output dtype follows probe flag.
//
// R17: 256^2 path closed (R16: swizzle zeroed conflicts 14.16M->0 but 108.9us
// > 128^2's 93.4 -> grid-tail (1.5 rounds @ 1blk/CU) + short-K amortization
// are structural; GEMM declared pinned ~550TF at this shape after 5
// structures). ERRATum: R6-family's 6.29M conflicts = 1 cyc/read = free
// 2-way, not 8-way. Redeploy to attn per m169: DROP V-staging only (V is
// pre-transposed; staging = pure overhead), keep K staged+prefetched (R7
// proved K destage is fatal). LDS 50->34KB -> 4 blk/CU; 2 fewer gl_lds per
// tile in the barrier drain. GEMMs = R14-exact (equal-best 93.4).

typedef __attribute__((ext_vector_type(8))) short bf16x8;
typedef __attribute__((ext_vector_type(4))) float f32x4;

__device__ inline short f2b(float f) {
  unsigned u = __float_as_uint(f);
  unsigned r = (u + 0x7fff + ((u >> 16) & 1)) >> 16;
  return (short)r;
}
__device__ inline float b2f(short s) {
  return __uint_as_float(((unsigned)(unsigned short)s) << 16);
}

__device__ inline bf16x8 ld8(const char* p, int isf32) {
  if (isf32) {
    const float* f = (const float*)p;
    bf16x8 r;
#pragma unroll
    for (int j = 0; j < 8; j++) r[j] = f2b(f[j]);
    return r;
  }
  return *(const bf16x8*)p;
}

__device__ inline float ldbias(const char* b, int n, int isf32) {
  return isf32 ? ((const float*)b)[n] : b2f(((const short*)b)[n]);
}

__device__ inline void gl_lds16(const short* g, short* l) {
  __builtin_amdgcn_global_load_lds(
      (const __attribute__((address_space(1))) void*)g,
      (__attribute__((address_space(3))) void*)l, 16, 0, 0);
}

// ---------------- dtype probe (1 block x 64) --------------------------------
__global__ void probe_k(const short* __restrict__ xs, int* __restrict__ flag) {
  int lane = threadIdx.x & 63;
  int cnt = 0;
  for (int i = lane; i < 1024; i += 64) {
    int e = (xs[2 * i] >> 7) & 0xFF;
    cnt += (e >= 0x90) ? 1 : 0;
  }
#pragma unroll
  for (int o = 1; o < 64; o <<= 1) cnt += __shfl_xor(cnt, o);
  if (lane == 0) *flag = (cnt > 100) ? 1 : 0;
}

// ---------------- x -> bf16 -------------------------------------------------
__global__ __launch_bounds__(256) void cvt_x_k(const char* __restrict__ x,
                                               short* __restrict__ xb,
                                               const int* __restrict__ flag,
                                               int b_base) {
  int isf32 = *flag;
  size_t esz = isf32 ? 4 : 2;
  size_t i = ((size_t)blockIdx.x * 256 + threadIdx.x) * 8;
  size_t g = (size_t)b_base * 1024 * 1024 + i;
  *(bf16x8*)(xb + i) = ld8(x + g * esz, isf32);
}

// ---------------- transpose out[c][r] = in[r][c] ----------------------------
__global__ __launch_bounds__(256) void transpose_k(
    const char* __restrict__ in, short* __restrict__ out, int R, int C,
    const int* __restrict__ flag) {
  __shared__ __align__(16) short tile[64][80];
  int isf32 = *flag;
  size_t esz = isf32 ? 4 : 2;
  int t = threadIdx.x;
  int r0 = blockIdx.y * 64, c0 = blockIdx.x * 64;
#pragma unroll
  for (int i = 0; i < 2; i++) {
    int s = i * 256 + t;
    int rr = s >> 3, cc = (s & 7) * 8;
    *(bf16x8*)&tile[rr][cc] =
        ld8(in + ((size_t)(r0 + rr) * C + c0 + cc) * esz, isf32);
  }
  __syncthreads();
#pragma unroll
  for (int i = 0; i < 2; i++) {
    int s = i * 256 + t;
    int cc2 = s >> 3, rr2 = (s & 7) * 8;
    bf16x8 v;
#pragma unroll
    for (int j = 0; j < 8; j++) v[j] = tile[rr2 + j][cc2];
    *(bf16x8*)(out + (size_t)(c0 + cc2) * R + r0 + rr2) = v;
  }
}

// ---------------- GEMM core (R14): 128x128, K=1024 --------------------------
// 3 buffers x BK=32, prefetch distance 2, counted vmcnt(8/4/0), raw barriers.
template <int CUR, int MODE>
__device__ __forceinline__ void gstep(const short* __restrict__ Ab,
                                      const short* __restrict__ Bb, short* Ls,
                                      int ktn, int t, int srow, int lk, int wm,
                                      int wn, int col, int quad,
                                      f32x4 (&acc)[4][4]) {
  if (MODE == 0) {
    constexpr int SB = (CUR + 2) % 3;
    short* Ad = Ls + SB * 8192;
    short* Bd = Ad + 4096;
    gl_lds16(Ab + (size_t)srow * 1024 + ktn + lk, Ad + t * 8);
    gl_lds16(Ab + (size_t)(srow + 64) * 1024 + ktn + lk, Ad + 2048 + t * 8);
    gl_lds16(Bb + (size_t)srow * 1024 + ktn + lk, Bd + t * 8);
    gl_lds16(Bb + (size_t)(srow + 64) * 1024 + ktn + lk, Bd + 2048 + t * 8);
    asm volatile("s_waitcnt vmcnt(8)" ::: "memory");
  } else if (MODE == 1) {
    asm volatile("s_waitcnt vmcnt(4)" ::: "memory");
  } else {
    asm volatile("s_waitcnt vmcnt(0)" ::: "memory");
  }
  __builtin_amdgcn_sched_barrier(0);
  __builtin_amdgcn_s_barrier();

  const short* Ac = Ls + CUR * 8192;
  const short* Bc = Ac + 4096;
  bf16x8 af[4], bfr[4];
#pragma unroll
  for (int i = 0; i < 4; i++)
    af[i] = *(const bf16x8*)(Ac + (wm + i * 16 + col) * 32 + quad * 8);
#pragma unroll
  for (int i = 0; i < 4; i++)
    bfr[i] = *(const bf16x8*)(Bc + (wn + i * 16 + col) * 32 + quad * 8);
  __builtin_amdgcn_s_setprio(1);
#pragma unroll
  for (int i = 0; i < 4; i++)
#pragma unroll
    for (int j = 0; j < 4; j++)
      acc[i][j] = __builtin_amdgcn_mfma_f32_16x16x32_bf16(af[i], bfr[j],
                                                          acc[i][j], 0, 0, 0);
  __builtin_amdgcn_s_setprio(0);
  __builtin_amdgcn_s_barrier();
}

__device__ inline void gemm_core(const short* __restrict__ A,
                                 const short* __restrict__ Bt, short* Ls,
                                 int m0, int n0, f32x4 (&acc)[4][4]) {
  int t = threadIdx.x;
  int lane = t & 63, wave = t >> 6, quad = lane >> 4, col = lane & 15;
  int wm = (wave >> 1) * 64, wn = (wave & 1) * 64;
  const short* Ab = A + (size_t)m0 * 1024;
  const short* Bb = Bt + (size_t)n0 * 1024;
  int srow = t >> 2, lk = (t & 3) * 8;

  gl_lds16(Ab + (size_t)srow * 1024 + lk, Ls + t * 8);
  gl_lds16(Ab + (size_t)(srow + 64) * 1024 + lk, Ls + 2048 + t * 8);
  gl_lds16(Bb + (size_t)srow * 1024 + lk, Ls + 4096 + t * 8);
  gl_lds16(Bb + (size_t)(srow + 64) * 1024 + lk, Ls + 4096 + 2048 + t * 8);
  gl_lds16(Ab + (size_t)srow * 1024 + 32 + lk, Ls + 8192 + t * 8);
  gl_lds16(Ab + (size_t)(srow + 64) * 1024 + 32 + lk, Ls + 8192 + 2048 + t * 8);
  gl_lds16(Bb + (size_t)srow * 1024 + 32 + lk, Ls + 8192 + 4096 + t * 8);
  gl_lds16(Bb + (size_t)(srow + 64) * 1024 + 32 + lk,
           Ls + 8192 + 4096 + 2048 + t * 8);

  for (int g = 0; g < 10; g++) {
    int kb = g * 96;
    gstep<0, 0>(Ab, Bb, Ls, kb + 64, t, srow, lk, wm, wn, col, quad, acc);
    gstep<1, 0>(Ab, Bb, Ls, kb + 96, t, srow, lk, wm, wn, col, quad, acc);
    gstep<2, 0>(Ab, Bb, Ls, kb + 128, t, srow, lk, wm, wn, col, quad, acc);
  }
  gstep<0, 1>(Ab, Bb, Ls, 0, t, srow, lk, wm, wn, col, quad, acc);
  gstep<1, 2>(Ab, Bb, Ls, 0, t, srow, lk, wm, wn, col, quad, acc);
}

// GEMM1. Grid (24, nb*8). Q pre-scaled by 0.125 (exact).
__global__ __launch_bounds__(256, 3) void gemm_qkv_k(
    const short* __restrict__ xbf, const short* __restrict__ wT,
    const char* __restrict__ bias, short* __restrict__ Qb,
    short* __restrict__ Kb, short* __restrict__ VTb,
    const int* __restrict__ flag) {
  __shared__ __align__(16) short Ls[3 * 8192];
  int isf32 = *flag;
  f32x4 acc[4][4];
#pragma unroll
  for (int i = 0; i < 4; i++)
#pragma unroll
    for (int j = 0; j < 4; j++) acc[i][j] = f32x4{0.f, 0.f, 0.f, 0.f};
  int m0 = blockIdx.y * 128, n0 = blockIdx.x * 128;
  gemm_core(xbf, wT, Ls, m0, n0, acc);
  int t = threadIdx.x, wave = t >> 6, lane = t & 63, quad = lane >> 4,
      col = lane & 15;
  int wm = (wave >> 1) * 64, wn = (wave & 1) * 64;
#pragma unroll
  for (int j = 0; j < 4; j++) {
    int n = n0 + wn + j * 16 + col;
    float bv = ldbias(bias, n, isf32);
    int qi = n >> 10, d = n & 1023, h = d >> 6, dh = d & 63;
#pragma unroll
    for (int i = 0; i < 4; i++) {
#pragma unroll
      for (int r = 0; r < 4; r++) {
        int m = m0 + wm + i * 16 + quad * 4 + r;
        int bl = m >> 10, tp = m & 1023;
        size_t bh = (size_t)bl * 16 + h;
        float val = acc[i][j][r] + bv;
        if (qi == 0)
          Qb[(bh * 1024 + tp) * 64 + dh] = f2b(val * 0.125f);
        else if (qi == 1)
          Kb[(bh * 1024 + tp) * 64 + dh] = f2b(val);
        else
          VTb[(bh * 64 + dh) * 1024 + tp] = f2b(val);
      }
    }
  }
}

// attention. Grid (8, nb*16), 4 waves; each wave owns 32 q-rows (2 q-tiles).
// R17: K staged + distance-1 prefetch dbuf (R8-exact path); V read DIRECTLY
// from global in the PV loop (m169: V-staging of pre-transposed, L2-resident
// V is pure overhead). LDS 34KB -> 4 blk/CU. Wave-private P round-trip;
// early-exit zero-fill.
__global__ __launch_bounds__(256, 4) void attn_k(
    const short* __restrict__ Qb, const short* __restrict__ Kb,
    const short* __restrict__ VTb, const int* __restrict__ lengths,
    short* __restrict__ Ob, int b_base) {
  __shared__ __align__(16) short Ks[2][2][64 * 32];  // [buf][half][key][d]
  __shared__ __align__(16) short Pl[4 * 32 * 72];
  int t = threadIdx.x, wave = t >> 6, lane = t & 63, quad = lane >> 4,
      col = lane & 15;
  int bh = blockIdx.y, bl = bh >> 4, h = bh & 15;
  int len = lengths[b_base + bl];
  int qblk = blockIdx.x * 128;
  if (qblk >= len) {
    bf16x8 z;
#pragma unroll
    for (int j = 0; j < 8; j++) z[j] = 0;
    int rr = t >> 1, cc = (t & 1) * 32;
    short* dst = Ob + ((size_t)bl * 1024 + qblk + rr) * 1024 + h * 64 + cc;
#pragma unroll
    for (int j = 0; j < 4; j++) *(bf16x8*)(dst + j * 8) = z;
    return;
  }
  int qb0 = qblk + wave * 16;  // qt adds +64
  const short* Q = Qb + (size_t)bh * 1024 * 64;
  const short* K = Kb + (size_t)bh * 1024 * 64;
  const short* VT = VTb + (size_t)bh * 64 * 1024;
  short* myP = Pl + wave * 32 * 72;

  int srow = t >> 2, skk = (t & 3) * 8;

  bf16x8 qf[2][2];
#pragma unroll
  for (int qt = 0; qt < 2; qt++) {
    qf[qt][0] = *(const bf16x8*)(Q + (qb0 + qt * 64 + col) * 64 + quad * 8);
    qf[qt][1] =
        *(const bf16x8*)(Q + (qb0 + qt * 64 + col) * 64 + 32 + quad * 8);
  }

  f32x4 oacc[2][4];
  float suml[2][4];
#pragma unroll
  for (int qt = 0; qt < 2; qt++)
#pragma unroll
    for (int i = 0; i < 4; i++) {
      oacc[qt][i] = f32x4{0.f, 0.f, 0.f, 0.f};
      suml[qt][i] = 0.f;
    }

  int klim = ((len + 63) >> 6) << 6;  // block-uniform, <= 1024

  gl_lds16(K + (size_t)srow * 64 + skk, Ks[0][0] + t * 8);
  gl_lds16(K + (size_t)srow * 64 + 32 + skk, Ks[0][1] + t * 8);
  __syncthreads();

  for (int k0 = 0; k0 < klim; k0 += 64) {
    int cur = (k0 >> 6) & 1;
    if (k0 + 64 < klim) {
      int nx = cur ^ 1, kn = k0 + 64;
      gl_lds16(K + (size_t)(kn + srow) * 64 + skk, Ks[nx][0] + t * 8);
      gl_lds16(K + (size_t)(kn + srow) * 64 + 32 + skk, Ks[nx][1] + t * 8);
    }

#pragma unroll
    for (int qt = 0; qt < 2; qt++) {
      f32x4 s[4];
#pragma unroll
      for (int ks = 0; ks < 4; ks++) s[ks] = f32x4{0.f, 0.f, 0.f, 0.f};
      __builtin_amdgcn_s_setprio(1);
#pragma unroll
      for (int ks = 0; ks < 4; ks++) {
        bf16x8 klo =
            *(const bf16x8*)(Ks[cur][0] + (ks * 16 + col) * 32 + quad * 8);
        bf16x8 khi =
            *(const bf16x8*)(Ks[cur][1] + (ks * 16 + col) * 32 + quad * 8);
        s[ks] = __builtin_amdgcn_mfma_f32_16x16x32_bf16(qf[qt][0], klo, s[ks],
                                                        0, 0, 0);
        s[ks] = __builtin_amdgcn_mfma_f32_16x16x32_bf16(qf[qt][1], khi, s[ks],
                                                        0, 0, 0);
      }
      __builtin_amdgcn_s_setprio(0);
#pragma unroll
      for (int ks = 0; ks < 4; ks++) {
#pragma unroll
        for (int r = 0; r < 4; r++) {
          float e = (k0 + ks * 16 + col < len) ? __expf(s[ks][r]) : 0.f;
          suml[qt][r] += e;
          myP[(qt * 16 + quad * 4 + r) * 72 + ks * 16 + col] = f2b(e);
        }
      }
    }
    // PV: P from wave-private LDS; V straight from global (L2-hit), covered
    // by the MFMA chain + 4 blk/CU TLP.
#pragma unroll
    for (int qt = 0; qt < 2; qt++) {
      bf16x8 pf0 = *(const bf16x8*)(myP + (qt * 16 + col) * 72 + quad * 8);
      bf16x8 pf1 = *(const bf16x8*)(myP + (qt * 16 + col) * 72 + 32 + quad * 8);
      __builtin_amdgcn_s_setprio(1);
#pragma unroll
      for (int nt = 0; nt < 4; nt++) {
        bf16x8 v0 = *(const bf16x8*)(VT + (size_t)(nt * 16 + col) * 1024 + k0 +
                                     quad * 8);
        bf16x8 v1 = *(const bf16x8*)(VT + (size_t)(nt * 16 + col) * 1024 + k0 +
                                     32 + quad * 8);
        oacc[qt][nt] = __builtin_amdgcn_mfma_f32_16x16x32_bf16(
            pf0, v0, oacc[qt][nt], 0, 0, 0);
        oacc[qt][nt] = __builtin_amdgcn_mfma_f32_16x16x32_bf16(
            pf1, v1, oacc[qt][nt], 0, 0, 0);
      }
      __builtin_amdgcn_s_setprio(0);
    }
    __syncthreads();
  }
#pragma unroll
  for (int qt = 0; qt < 2; qt++)
#pragma unroll
    for (int r = 0; r < 4; r++) {
      suml[qt][r] += __shfl_xor(suml[qt][r], 1);
      suml[qt][r] += __shfl_xor(suml[qt][r], 2);
      suml[qt][r] += __shfl_xor(suml[qt][r], 4);
      suml[qt][r] += __shfl_xor(suml[qt][r], 8);
    }
#pragma unroll
  for (int qt = 0; qt < 2; qt++)
#pragma unroll
    for (int nt = 0; nt < 4; nt++)
#pragma unroll
      for (int r = 0; r < 4; r++) {
        int q = qb0 + qt * 64 + quad * 4 + r;
        float v = (q < len) ? oacc[qt][nt][r] / suml[qt][r] : 0.f;
        Ob[((size_t)bl * 1024 + q) * 1024 + h * 64 + nt * 16 + col] = f2b(v);
      }
}

// GEMM2. Grid (8, nb*8). Output dtype follows flag.
__global__ __launch_bounds__(256, 3) void gemm_out_k(
    const short* __restrict__ O, const short* __restrict__ wT,
    const char* __restrict__ bias, char* __restrict__ out,
    const int* __restrict__ flag, int m_base) {
  __shared__ __align__(16) short Ls[3 * 8192];
  int isf32 = *flag;
  f32x4 acc[4][4];
#pragma unroll
  for (int i = 0; i < 4; i++)
#pragma unroll
    for (int j = 0; j < 4; j++) acc[i][j] = f32x4{0.f, 0.f, 0.f, 0.f};
  int m0 = blockIdx.y * 128, n0 = blockIdx.x * 128;
  gemm_core(O, wT, Ls, m0, n0, acc);
  int t = threadIdx.x, wave = t >> 6, lane = t & 63, quad = lane >> 4,
      col = lane & 15;
  int wm = (wave >> 1) * 64, wn = (wave & 1) * 64;
#pragma unroll
  for (int j = 0; j < 4; j++) {
    int n = n0 + wn + j * 16 + col;
    float bv = ldbias(bias, n, isf32);
#pragma unroll
    for (int i = 0; i < 4; i++) {
#pragma unroll
      for (int r = 0; r < 4; r++) {
        int m = m0 + wm + i * 16 + quad * 4 + r;
        size_t idx = (size_t)(m_base + m) * 1024 + n;
        float val = acc[i][j][r] + bv;
        if (isf32)
          ((float*)out)[idx] = val;
        else
          ((short*)out)[idx] = f2b(val);
      }
    }
  }
}

extern "C" void kernel_launch(void* const* d_in, const int* in_sizes, int n_in,
                              void* d_out, int out_size, void* d_ws,
                              size_t ws_size, hipStream_t stream) {
  const char* x = (const char*)d_in[0];
  const int* lengths = (const int*)d_in[1];
  const char* w_qkv = (const char*)d_in[2];
  const char* b_qkv = (const char*)d_in[3];
  const char* w_o = (const char*)d_in[4];
  const char* b_o = (const char*)d_in[5];
  char* out = (char*)d_out;

  char* ws = (char*)d_ws;
  int* flag = (int*)ws;        ws += 256;
  short* wT_qkv = (short*)ws;  ws += (size_t)3072 * 1024 * 2;  // 6.3 MB
  short* wT_o = (short*)ws;    ws += (size_t)1024 * 1024 * 2;  // 2.1 MB
  char* dynbase = ws;
  size_t fixed = (size_t)(dynbase - (char*)d_ws);
  size_t per_batch = (size_t)16 * 1024 * 64 * 2;  // 2.10 MB / tensor
  size_t need_full = fixed + 4 * 8 * per_batch;   // ~75.8 MB (fits, R3-R5)
  int nb = (ws_size >= need_full) ? 8 : 1;

  // xbf aliases Ob: x consumed by GEMM1 before attn writes Ob.
  short* xbf_Ob = (short*)dynbase;
  short* Qb = xbf_Ob + (size_t)nb * 16 * 1024 * 64;
  short* Kb = Qb + (size_t)nb * 16 * 1024 * 64;
  short* VTb = Kb + (size_t)nb * 16 * 1024 * 64;

  dim3 blk(256);
  probe_k<<<1, 64, 0, stream>>>((const short*)x, flag);
  transpose_k<<<dim3(48, 16), blk, 0, stream>>>(w_qkv, wT_qkv, 1024, 3072, flag);
  transpose_k<<<dim3(16, 16), blk, 0, stream>>>(w_o, wT_o, 1024, 1024, flag);
  for (int b0 = 0; b0 < 8; b0 += nb) {
    cvt_x_k<<<dim3(nb * 512), blk, 0, stream>>>(x, xbf_Ob, flag, b0);
    gemm_qkv_k<<<dim3(24, nb * 8), blk, 0, stream>>>(xbf_Ob, wT_qkv, b_qkv, Qb,
                                                     Kb, VTb, flag);
    attn_k<<<dim3(8, nb * 16), blk, 0, stream>>>(Qb, Kb, VTb, lengths, xbf_Ob,
                                                 b0);
    gemm_out_k<<<dim3(8, nb * 8), blk, 0, stream>>>(xbf_Ob, wT_o, b_o, out,
                                                    flag, b0 * 1024);
  }
}

// Round 12
// 272.933 us; speedup vs baseline: 1.1007x; 1.0283x over previous
//
#include <hip/hip_runtime.h>

// B=8, T=1024, D=1024, H=16, Dh=64. x/w/b fp32 (probe-verified; dual path
// kept), lengths int32, output dtype follows probe flag.
//
// R18: consolidation + T14. Ledger across R15-R17: rest(total-gemm) = 177-178
// with R8-exact attn vs 187 with R17's V-destage -> V-in-PV-loop costs 10us
// (no issue distance). Best pairing never benched: R14 gemm (93.4) + R8 attn.
// This round: that pairing, with V moved to REGISTER prefetch with issue
// distance (T14, m214 v27 +17% attn): V-frag global loads for nt{0,1} issued
// BEFORE the QK MFMA section (~600cy cover), nt{2,3} before the P roundtrip
// (~200cy cover). K stays LDS-staged dbuf (R7: K destage fatal). No new
// sync; LDS 50->34KB; 4 blk/CU.

typedef __attribute__((ext_vector_type(8))) short bf16x8;
typedef __attribute__((ext_vector_type(4))) float f32x4;

__device__ inline short f2b(float f) {
  unsigned u = __float_as_uint(f);
  unsigned r = (u + 0x7fff + ((u >> 16) & 1)) >> 16;
  return (short)r;
}
__device__ inline float b2f(short s) {
  return __uint_as_float(((unsigned)(unsigned short)s) << 16);
}

__device__ inline bf16x8 ld8(const char* p, int isf32) {
  if (isf32) {
    const float* f = (const float*)p;
    bf16x8 r;
#pragma unroll
    for (int j = 0; j < 8; j++) r[j] = f2b(f[j]);
    return r;
  }
  return *(const bf16x8*)p;
}

__device__ inline float ldbias(const char* b, int n, int isf32) {
  return isf32 ? ((const float*)b)[n] : b2f(((const short*)b)[n]);
}

__device__ inline void gl_lds16(const short* g, short* l) {
  __builtin_amdgcn_global_load_lds(
      (const __attribute__((address_space(1))) void*)g,
      (__attribute__((address_space(3))) void*)l, 16, 0, 0);
}

// ---------------- dtype probe (1 block x 64) --------------------------------
__global__ void probe_k(const short* __restrict__ xs, int* __restrict__ flag) {
  int lane = threadIdx.x & 63;
  int cnt = 0;
  for (int i = lane; i < 1024; i += 64) {
    int e = (xs[2 * i] >> 7) & 0xFF;
    cnt += (e >= 0x90) ? 1 : 0;
  }
#pragma unroll
  for (int o = 1; o < 64; o <<= 1) cnt += __shfl_xor(cnt, o);
  if (lane == 0) *flag = (cnt > 100) ? 1 : 0;
}

// ---------------- x -> bf16 -------------------------------------------------
__global__ __launch_bounds__(256) void cvt_x_k(const char* __restrict__ x,
                                               short* __restrict__ xb,
                                               const int* __restrict__ flag,
                                               int b_base) {
  int isf32 = *flag;
  size_t esz = isf32 ? 4 : 2;
  size_t i = ((size_t)blockIdx.x * 256 + threadIdx.x) * 8;
  size_t g = (size_t)b_base * 1024 * 1024 + i;
  *(bf16x8*)(xb + i) = ld8(x + g * esz, isf32);
}

// ---------------- transpose out[c][r] = in[r][c] ----------------------------
__global__ __launch_bounds__(256) void transpose_k(
    const char* __restrict__ in, short* __restrict__ out, int R, int C,
    const int* __restrict__ flag) {
  __shared__ __align__(16) short tile[64][80];
  int isf32 = *flag;
  size_t esz = isf32 ? 4 : 2;
  int t = threadIdx.x;
  int r0 = blockIdx.y * 64, c0 = blockIdx.x * 64;
#pragma unroll
  for (int i = 0; i < 2; i++) {
    int s = i * 256 + t;
    int rr = s >> 3, cc = (s & 7) * 8;
    *(bf16x8*)&tile[rr][cc] =
        ld8(in + ((size_t)(r0 + rr) * C + c0 + cc) * esz, isf32);
  }
  __syncthreads();
#pragma unroll
  for (int i = 0; i < 2; i++) {
    int s = i * 256 + t;
    int cc2 = s >> 3, rr2 = (s & 7) * 8;
    bf16x8 v;
#pragma unroll
    for (int j = 0; j < 8; j++) v[j] = tile[rr2 + j][cc2];
    *(bf16x8*)(out + (size_t)(c0 + cc2) * R + r0 + rr2) = v;
  }
}

// ---------------- GEMM core (R14): 128x128, K=1024 --------------------------
// 3 buffers x BK=32, prefetch distance 2, counted vmcnt(8/4/0), raw barriers.
template <int CUR, int MODE>
__device__ __forceinline__ void gstep(const short* __restrict__ Ab,
                                      const short* __restrict__ Bb, short* Ls,
                                      int ktn, int t, int srow, int lk, int wm,
                                      int wn, int col, int quad,
                                      f32x4 (&acc)[4][4]) {
  if (MODE == 0) {
    constexpr int SB = (CUR + 2) % 3;
    short* Ad = Ls + SB * 8192;
    short* Bd = Ad + 4096;
    gl_lds16(Ab + (size_t)srow * 1024 + ktn + lk, Ad + t * 8);
    gl_lds16(Ab + (size_t)(srow + 64) * 1024 + ktn + lk, Ad + 2048 + t * 8);
    gl_lds16(Bb + (size_t)srow * 1024 + ktn + lk, Bd + t * 8);
    gl_lds16(Bb + (size_t)(srow + 64) * 1024 + ktn + lk, Bd + 2048 + t * 8);
    asm volatile("s_waitcnt vmcnt(8)" ::: "memory");
  } else if (MODE == 1) {
    asm volatile("s_waitcnt vmcnt(4)" ::: "memory");
  } else {
    asm volatile("s_waitcnt vmcnt(0)" ::: "memory");
  }
  __builtin_amdgcn_sched_barrier(0);
  __builtin_amdgcn_s_barrier();

  const short* Ac = Ls + CUR * 8192;
  const short* Bc = Ac + 4096;
  bf16x8 af[4], bfr[4];
#pragma unroll
  for (int i = 0; i < 4; i++)
    af[i] = *(const bf16x8*)(Ac + (wm + i * 16 + col) * 32 + quad * 8);
#pragma unroll
  for (int i = 0; i < 4; i++)
    bfr[i] = *(const bf16x8*)(Bc + (wn + i * 16 + col) * 32 + quad * 8);
  __builtin_amdgcn_s_setprio(1);
#pragma unroll
  for (int i = 0; i < 4; i++)
#pragma unroll
    for (int j = 0; j < 4; j++)
      acc[i][j] = __builtin_amdgcn_mfma_f32_16x16x32_bf16(af[i], bfr[j],
                                                          acc[i][j], 0, 0, 0);
  __builtin_amdgcn_s_setprio(0);
  __builtin_amdgcn_s_barrier();
}

__device__ inline void gemm_core(const short* __restrict__ A,
                                 const short* __restrict__ Bt, short* Ls,
                                 int m0, int n0, f32x4 (&acc)[4][4]) {
  int t = threadIdx.x;
  int lane = t & 63, wave = t >> 6, quad = lane >> 4, col = lane & 15;
  int wm = (wave >> 1) * 64, wn = (wave & 1) * 64;
  const short* Ab = A + (size_t)m0 * 1024;
  const short* Bb = Bt + (size_t)n0 * 1024;
  int srow = t >> 2, lk = (t & 3) * 8;

  gl_lds16(Ab + (size_t)srow * 1024 + lk, Ls + t * 8);
  gl_lds16(Ab + (size_t)(srow + 64) * 1024 + lk, Ls + 2048 + t * 8);
  gl_lds16(Bb + (size_t)srow * 1024 + lk, Ls + 4096 + t * 8);
  gl_lds16(Bb + (size_t)(srow + 64) * 1024 + lk, Ls + 4096 + 2048 + t * 8);
  gl_lds16(Ab + (size_t)srow * 1024 + 32 + lk, Ls + 8192 + t * 8);
  gl_lds16(Ab + (size_t)(srow + 64) * 1024 + 32 + lk, Ls + 8192 + 2048 + t * 8);
  gl_lds16(Bb + (size_t)srow * 1024 + 32 + lk, Ls + 8192 + 4096 + t * 8);
  gl_lds16(Bb + (size_t)(srow + 64) * 1024 + 32 + lk,
           Ls + 8192 + 4096 + 2048 + t * 8);

  for (int g = 0; g < 10; g++) {
    int kb = g * 96;
    gstep<0, 0>(Ab, Bb, Ls, kb + 64, t, srow, lk, wm, wn, col, quad, acc);
    gstep<1, 0>(Ab, Bb, Ls, kb + 96, t, srow, lk, wm, wn, col, quad, acc);
    gstep<2, 0>(Ab, Bb, Ls, kb + 128, t, srow, lk, wm, wn, col, quad, acc);
  }
  gstep<0, 1>(Ab, Bb, Ls, 0, t, srow, lk, wm, wn, col, quad, acc);
  gstep<1, 2>(Ab, Bb, Ls, 0, t, srow, lk, wm, wn, col, quad, acc);
}

// GEMM1. Grid (24, nb*8). Q pre-scaled by 0.125 (exact).
__global__ __launch_bounds__(256, 3) void gemm_qkv_k(
    const short* __restrict__ xbf, const short* __restrict__ wT,
    const char* __restrict__ bias, short* __restrict__ Qb,
    short* __restrict__ Kb, short* __restrict__ VTb,
    const int* __restrict__ flag) {
  __shared__ __align__(16) short Ls[3 * 8192];
  int isf32 = *flag;
  f32x4 acc[4][4];
#pragma unroll
  for (int i = 0; i < 4; i++)
#pragma unroll
    for (int j = 0; j < 4; j++) acc[i][j] = f32x4{0.f, 0.f, 0.f, 0.f};
  int m0 = blockIdx.y * 128, n0 = blockIdx.x * 128;
  gemm_core(xbf, wT, Ls, m0, n0, acc);
  int t = threadIdx.x, wave = t >> 6, lane = t & 63, quad = lane >> 4,
      col = lane & 15;
  int wm = (wave >> 1) * 64, wn = (wave & 1) * 64;
#pragma unroll
  for (int j = 0; j < 4; j++) {
    int n = n0 + wn + j * 16 + col;
    float bv = ldbias(bias, n, isf32);
    int qi = n >> 10, d = n & 1023, h = d >> 6, dh = d & 63;
#pragma unroll
    for (int i = 0; i < 4; i++) {
#pragma unroll
      for (int r = 0; r < 4; r++) {
        int m = m0 + wm + i * 16 + quad * 4 + r;
        int bl = m >> 10, tp = m & 1023;
        size_t bh = (size_t)bl * 16 + h;
        float val = acc[i][j][r] + bv;
        if (qi == 0)
          Qb[(bh * 1024 + tp) * 64 + dh] = f2b(val * 0.125f);
        else if (qi == 1)
          Kb[(bh * 1024 + tp) * 64 + dh] = f2b(val);
        else
          VTb[(bh * 64 + dh) * 1024 + tp] = f2b(val);
      }
    }
  }
}

// attention. Grid (8, nb*16), 4 waves; each wave owns 32 q-rows (2 q-tiles).
// R18: R8-exact sync structure (K LDS-staged distance-1 dbuf, one
// __syncthreads per tile, wave-private P round-trip, early-exit) with V via
// T14 register prefetch: nt{0,1} frags loaded before QK (~600cy cover),
// nt{2,3} before the P round-trip. LDS 34KB -> 4 blk/CU.
__global__ __launch_bounds__(256, 4) void attn_k(
    const short* __restrict__ Qb, const short* __restrict__ Kb,
    const short* __restrict__ VTb, const int* __restrict__ lengths,
    short* __restrict__ Ob, int b_base) {
  __shared__ __align__(16) short Ks[2][2][64 * 32];  // [buf][half][key][d]
  __shared__ __align__(16) short Pl[4 * 32 * 72];
  int t = threadIdx.x, wave = t >> 6, lane = t & 63, quad = lane >> 4,
      col = lane & 15;
  int bh = blockIdx.y, bl = bh >> 4, h = bh & 15;
  int len = lengths[b_base + bl];
  int qblk = blockIdx.x * 128;
  if (qblk >= len) {
    bf16x8 z;
#pragma unroll
    for (int j = 0; j < 8; j++) z[j] = 0;
    int rr = t >> 1, cc = (t & 1) * 32;
    short* dst = Ob + ((size_t)bl * 1024 + qblk + rr) * 1024 + h * 64 + cc;
#pragma unroll
    for (int j = 0; j < 4; j++) *(bf16x8*)(dst + j * 8) = z;
    return;
  }
  int qb0 = qblk + wave * 16;  // qt adds +64
  const short* Q = Qb + (size_t)bh * 1024 * 64;
  const short* K = Kb + (size_t)bh * 1024 * 64;
  const short* VT = VTb + (size_t)bh * 64 * 1024;
  short* myP = Pl + wave * 32 * 72;

  int srow = t >> 2, skk = (t & 3) * 8;

  bf16x8 qf[2][2];
#pragma unroll
  for (int qt = 0; qt < 2; qt++) {
    qf[qt][0] = *(const bf16x8*)(Q + (qb0 + qt * 64 + col) * 64 + quad * 8);
    qf[qt][1] =
        *(const bf16x8*)(Q + (qb0 + qt * 64 + col) * 64 + 32 + quad * 8);
  }

  f32x4 oacc[2][4];
  float suml[2][4];
#pragma unroll
  for (int qt = 0; qt < 2; qt++)
#pragma unroll
    for (int i = 0; i < 4; i++) {
      oacc[qt][i] = f32x4{0.f, 0.f, 0.f, 0.f};
      suml[qt][i] = 0.f;
    }

  int klim = ((len + 63) >> 6) << 6;  // block-uniform, <= 1024

  gl_lds16(K + (size_t)srow * 64 + skk, Ks[0][0] + t * 8);
  gl_lds16(K + (size_t)srow * 64 + 32 + skk, Ks[0][1] + t * 8);
  __syncthreads();

  for (int k0 = 0; k0 < klim; k0 += 64) {
    int cur = (k0 >> 6) & 1;
    if (k0 + 64 < klim) {
      int nx = cur ^ 1, kn = k0 + 64;
      gl_lds16(K + (size_t)(kn + srow) * 64 + skk, Ks[nx][0] + t * 8);
      gl_lds16(K + (size_t)(kn + srow) * 64 + 32 + skk, Ks[nx][1] + t * 8);
    }

    // T14: issue V loads for nt=0,1 now; consumed after QK (~600cy cover).
    bf16x8 vr[4][2];
#pragma unroll
    for (int nt = 0; nt < 2; nt++) {
      vr[nt][0] = *(const bf16x8*)(VT + (size_t)(nt * 16 + col) * 1024 + k0 +
                                   quad * 8);
      vr[nt][1] = *(const bf16x8*)(VT + (size_t)(nt * 16 + col) * 1024 + k0 +
                                   32 + quad * 8);
    }

#pragma unroll
    for (int qt = 0; qt < 2; qt++) {
      f32x4 s[4];
#pragma unroll
      for (int ks = 0; ks < 4; ks++) s[ks] = f32x4{0.f, 0.f, 0.f, 0.f};
      __builtin_amdgcn_s_setprio(1);
#pragma unroll
      for (int ks = 0; ks < 4; ks++) {
        bf16x8 klo =
            *(const bf16x8*)(Ks[cur][0] + (ks * 16 + col) * 32 + quad * 8);
        bf16x8 khi =
            *(const bf16x8*)(Ks[cur][1] + (ks * 16 + col) * 32 + quad * 8);
        s[ks] = __builtin_amdgcn_mfma_f32_16x16x32_bf16(qf[qt][0], klo, s[ks],
                                                        0, 0, 0);
        s[ks] = __builtin_amdgcn_mfma_f32_16x16x32_bf16(qf[qt][1], khi, s[ks],
                                                        0, 0, 0);
      }
      __builtin_amdgcn_s_setprio(0);
#pragma unroll
      for (int ks = 0; ks < 4; ks++) {
#pragma unroll
        for (int r = 0; r < 4; r++) {
          float e = (k0 + ks * 16 + col < len) ? __expf(s[ks][r]) : 0.f;
          suml[qt][r] += e;
          myP[(qt * 16 + quad * 4 + r) * 72 + ks * 16 + col] = f2b(e);
        }
      }
    }

    // T14: issue V loads for nt=2,3; consumed after the P round-trip.
#pragma unroll
    for (int nt = 2; nt < 4; nt++) {
      vr[nt][0] = *(const bf16x8*)(VT + (size_t)(nt * 16 + col) * 1024 + k0 +
                                   quad * 8);
      vr[nt][1] = *(const bf16x8*)(VT + (size_t)(nt * 16 + col) * 1024 + k0 +
                                   32 + quad * 8);
    }

#pragma unroll
    for (int qt = 0; qt < 2; qt++) {
      bf16x8 pf0 = *(const bf16x8*)(myP + (qt * 16 + col) * 72 + quad * 8);
      bf16x8 pf1 = *(const bf16x8*)(myP + (qt * 16 + col) * 72 + 32 + quad * 8);
      __builtin_amdgcn_s_setprio(1);
#pragma unroll
      for (int nt = 0; nt < 4; nt++) {
        oacc[qt][nt] = __builtin_amdgcn_mfma_f32_16x16x32_bf16(
            pf0, vr[nt][0], oacc[qt][nt], 0, 0, 0);
        oacc[qt][nt] = __builtin_amdgcn_mfma_f32_16x16x32_bf16(
            pf1, vr[nt][1], oacc[qt][nt], 0, 0, 0);
      }
      __builtin_amdgcn_s_setprio(0);
    }
    __syncthreads();
  }
#pragma unroll
  for (int qt = 0; qt < 2; qt++)
#pragma unroll
    for (int r = 0; r < 4; r++) {
      suml[qt][r] += __shfl_xor(suml[qt][r], 1);
      suml[qt][r] += __shfl_xor(suml[qt][r], 2);
      suml[qt][r] += __shfl_xor(suml[qt][r], 4);
      suml[qt][r] += __shfl_xor(suml[qt][r], 8);
    }
#pragma unroll
  for (int qt = 0; qt < 2; qt++)
#pragma unroll
    for (int nt = 0; nt < 4; nt++)
#pragma unroll
      for (int r = 0; r < 4; r++) {
        int q = qb0 + qt * 64 + quad * 4 + r;
        float v = (q < len) ? oacc[qt][nt][r] / suml[qt][r] : 0.f;
        Ob[((size_t)bl * 1024 + q) * 1024 + h * 64 + nt * 16 + col] = f2b(v);
      }
}

// GEMM2. Grid (8, nb*8). Output dtype follows flag.
__global__ __launch_bounds__(256, 3) void gemm_out_k(
    const short* __restrict__ O, const short* __restrict__ wT,
    const char* __restrict__ bias, char* __restrict__ out,
    const int* __restrict__ flag, int m_base) {
  __shared__ __align__(16) short Ls[3 * 8192];
  int isf32 = *flag;
  f32x4 acc[4][4];
#pragma unroll
  for (int i = 0; i < 4; i++)
#pragma unroll
    for (int j = 0; j < 4; j++) acc[i][j] = f32x4{0.f, 0.f, 0.f, 0.f};
  int m0 = blockIdx.y * 128, n0 = blockIdx.x * 128;
  gemm_core(O, wT, Ls, m0, n0, acc);
  int t = threadIdx.x, wave = t >> 6, lane = t & 63, quad = lane >> 4,
      col = lane & 15;
  int wm = (wave >> 1) * 64, wn = (wave & 1) * 64;
#pragma unroll
  for (int j = 0; j < 4; j++) {
    int n = n0 + wn + j * 16 + col;
    float bv = ldbias(bias, n, isf32);
#pragma unroll
    for (int i = 0; i < 4; i++) {
#pragma unroll
      for (int r = 0; r < 4; r++) {
        int m = m0 + wm + i * 16 + quad * 4 + r;
        size_t idx = (size_t)(m_base + m) * 1024 + n;
        float val = acc[i][j][r] + bv;
        if (isf32)
          ((float*)out)[idx] = val;
        else
          ((short*)out)[idx] = f2b(val);
      }
    }
  }
}

extern "C" void kernel_launch(void* const* d_in, const int* in_sizes, int n_in,
                              void* d_out, int out_size, void* d_ws,
                              size_t ws_size, hipStream_t stream) {
  const char* x = (const char*)d_in[0];
  const int* lengths = (const int*)d_in[1];
  const char* w_qkv = (const char*)d_in[2];
  const char* b_qkv = (const char*)d_in[3];
  const char* w_o = (const char*)d_in[4];
  const char* b_o = (const char*)d_in[5];
  char* out = (char*)d_out;

  char* ws = (char*)d_ws;
  int* flag = (int*)ws;        ws += 256;
  short* wT_qkv = (short*)ws;  ws += (size_t)3072 * 1024 * 2;  // 6.3 MB
  short* wT_o = (short*)ws;    ws += (size_t)1024 * 1024 * 2;  // 2.1 MB
  char* dynbase = ws;
  size_t fixed = (size_t)(dynbase - (char*)d_ws);
  size_t per_batch = (size_t)16 * 1024 * 64 * 2;  // 2.10 MB / tensor
  size_t need_full = fixed + 4 * 8 * per_batch;   // ~75.8 MB (fits, R3-R5)
  int nb = (ws_size >= need_full) ? 8 : 1;

  // xbf aliases Ob: x consumed by GEMM1 before attn writes Ob.
  short* xbf_Ob = (short*)dynbase;
  short* Qb = xbf_Ob + (size_t)nb * 16 * 1024 * 64;
  short* Kb = Qb + (size_t)nb * 16 * 1024 * 64;
  short* VTb = Kb + (size_t)nb * 16 * 1024 * 64;

  dim3 blk(256);
  probe_k<<<1, 64, 0, stream>>>((const short*)x, flag);
  transpose_k<<<dim3(48, 16), blk, 0, stream>>>(w_qkv, wT_qkv, 1024, 3072, flag);
  transpose_k<<<dim3(16, 16), blk, 0, stream>>>(w_o, wT_o, 1024, 1024, flag);
  for (int b0 = 0; b0 < 8; b0 += nb) {
    cvt_x_k<<<dim3(nb * 512), blk, 0, stream>>>(x, xbf_Ob, flag, b0);
    gemm_qkv_k<<<dim3(24, nb * 8), blk, 0, stream>>>(xbf_Ob, wT_qkv, b_qkv, Qb,
                                                     Kb, VTb, flag);
    attn_k<<<dim3(8, nb * 16), blk, 0, stream>>>(Qb, Kb, VTb, lengths, xbf_Ob,
                                                 b0);
    gemm_out_k<<<dim3(8, nb * 8), blk, 0, stream>>>(xbf_Ob, wT_o, b_o, out,
                                                    flag, b0 * 1024);
  }
}

// Round 13
// 264.373 us; speedup vs baseline: 1.1364x; 1.0324x over previous
//
#include <hip/hip_runtime.h>

// B=8, T=1024, D=1024, H=16, Dh=64. x/w/b fp32 (probe-verified; dual path
// kept), lengths int32, output dtype follows probe flag.
//
// R19 = R18 (272.9us best: R14 gemm + R8-attn-with-T14) + length-masked block
// skipping (pure work elimination, ~19% of M-blocks at avg len 768):
//   - gemm_qkv: block-uniform early return when mloc >= len. Read-set proof:
//     attn reads Q rows < ceil128(len) (all from computed blocks), K rows and
//     VT cols < klim = ceil64(len) <= ceil128(len) -> skipped Qb/Kb/VTb
//     regions are NEVER read; no zero-fill needed.
//   - gemm_out: rows >= len must equal b_o exactly (attn zeroes those O rows;
//     0 @ w_o + b_o = b_o). Skipped blocks write the bias broadcast directly
//     (lane = n-column, coalesced). Partial blocks stay computed (correct
//     automatically since Ob rows >= len are zero).

typedef __attribute__((ext_vector_type(8))) short bf16x8;
typedef __attribute__((ext_vector_type(4))) float f32x4;

__device__ inline short f2b(float f) {
  unsigned u = __float_as_uint(f);
  unsigned r = (u + 0x7fff + ((u >> 16) & 1)) >> 16;
  return (short)r;
}
__device__ inline float b2f(short s) {
  return __uint_as_float(((unsigned)(unsigned short)s) << 16);
}

__device__ inline bf16x8 ld8(const char* p, int isf32) {
  if (isf32) {
    const float* f = (const float*)p;
    bf16x8 r;
#pragma unroll
    for (int j = 0; j < 8; j++) r[j] = f2b(f[j]);
    return r;
  }
  return *(const bf16x8*)p;
}

__device__ inline float ldbias(const char* b, int n, int isf32) {
  return isf32 ? ((const float*)b)[n] : b2f(((const short*)b)[n]);
}

__device__ inline void gl_lds16(const short* g, short* l) {
  __builtin_amdgcn_global_load_lds(
      (const __attribute__((address_space(1))) void*)g,
      (__attribute__((address_space(3))) void*)l, 16, 0, 0);
}

// ---------------- dtype probe (1 block x 64) --------------------------------
__global__ void probe_k(const short* __restrict__ xs, int* __restrict__ flag) {
  int lane = threadIdx.x & 63;
  int cnt = 0;
  for (int i = lane; i < 1024; i += 64) {
    int e = (xs[2 * i] >> 7) & 0xFF;
    cnt += (e >= 0x90) ? 1 : 0;
  }
#pragma unroll
  for (int o = 1; o < 64; o <<= 1) cnt += __shfl_xor(cnt, o);
  if (lane == 0) *flag = (cnt > 100) ? 1 : 0;
}

// ---------------- x -> bf16 -------------------------------------------------
__global__ __launch_bounds__(256) void cvt_x_k(const char* __restrict__ x,
                                               short* __restrict__ xb,
                                               const int* __restrict__ flag,
                                               int b_base) {
  int isf32 = *flag;
  size_t esz = isf32 ? 4 : 2;
  size_t i = ((size_t)blockIdx.x * 256 + threadIdx.x) * 8;
  size_t g = (size_t)b_base * 1024 * 1024 + i;
  *(bf16x8*)(xb + i) = ld8(x + g * esz, isf32);
}

// ---------------- transpose out[c][r] = in[r][c] ----------------------------
__global__ __launch_bounds__(256) void transpose_k(
    const char* __restrict__ in, short* __restrict__ out, int R, int C,
    const int* __restrict__ flag) {
  __shared__ __align__(16) short tile[64][80];
  int isf32 = *flag;
  size_t esz = isf32 ? 4 : 2;
  int t = threadIdx.x;
  int r0 = blockIdx.y * 64, c0 = blockIdx.x * 64;
#pragma unroll
  for (int i = 0; i < 2; i++) {
    int s = i * 256 + t;
    int rr = s >> 3, cc = (s & 7) * 8;
    *(bf16x8*)&tile[rr][cc] =
        ld8(in + ((size_t)(r0 + rr) * C + c0 + cc) * esz, isf32);
  }
  __syncthreads();
#pragma unroll
  for (int i = 0; i < 2; i++) {
    int s = i * 256 + t;
    int cc2 = s >> 3, rr2 = (s & 7) * 8;
    bf16x8 v;
#pragma unroll
    for (int j = 0; j < 8; j++) v[j] = tile[rr2 + j][cc2];
    *(bf16x8*)(out + (size_t)(c0 + cc2) * R + r0 + rr2) = v;
  }
}

// ---------------- GEMM core (R14): 128x128, K=1024 --------------------------
// 3 buffers x BK=32, prefetch distance 2, counted vmcnt(8/4/0), raw barriers.
template <int CUR, int MODE>
__device__ __forceinline__ void gstep(const short* __restrict__ Ab,
                                      const short* __restrict__ Bb, short* Ls,
                                      int ktn, int t, int srow, int lk, int wm,
                                      int wn, int col, int quad,
                                      f32x4 (&acc)[4][4]) {
  if (MODE == 0) {
    constexpr int SB = (CUR + 2) % 3;
    short* Ad = Ls + SB * 8192;
    short* Bd = Ad + 4096;
    gl_lds16(Ab + (size_t)srow * 1024 + ktn + lk, Ad + t * 8);
    gl_lds16(Ab + (size_t)(srow + 64) * 1024 + ktn + lk, Ad + 2048 + t * 8);
    gl_lds16(Bb + (size_t)srow * 1024 + ktn + lk, Bd + t * 8);
    gl_lds16(Bb + (size_t)(srow + 64) * 1024 + ktn + lk, Bd + 2048 + t * 8);
    asm volatile("s_waitcnt vmcnt(8)" ::: "memory");
  } else if (MODE == 1) {
    asm volatile("s_waitcnt vmcnt(4)" ::: "memory");
  } else {
    asm volatile("s_waitcnt vmcnt(0)" ::: "memory");
  }
  __builtin_amdgcn_sched_barrier(0);
  __builtin_amdgcn_s_barrier();

  const short* Ac = Ls + CUR * 8192;
  const short* Bc = Ac + 4096;
  bf16x8 af[4], bfr[4];
#pragma unroll
  for (int i = 0; i < 4; i++)
    af[i] = *(const bf16x8*)(Ac + (wm + i * 16 + col) * 32 + quad * 8);
#pragma unroll
  for (int i = 0; i < 4; i++)
    bfr[i] = *(const bf16x8*)(Bc + (wn + i * 16 + col) * 32 + quad * 8);
  __builtin_amdgcn_s_setprio(1);
#pragma unroll
  for (int i = 0; i < 4; i++)
#pragma unroll
    for (int j = 0; j < 4; j++)
      acc[i][j] = __builtin_amdgcn_mfma_f32_16x16x32_bf16(af[i], bfr[j],
                                                          acc[i][j], 0, 0, 0);
  __builtin_amdgcn_s_setprio(0);
  __builtin_amdgcn_s_barrier();
}

__device__ inline void gemm_core(const short* __restrict__ A,
                                 const short* __restrict__ Bt, short* Ls,
                                 int m0, int n0, f32x4 (&acc)[4][4]) {
  int t = threadIdx.x;
  int lane = t & 63, wave = t >> 6, quad = lane >> 4, col = lane & 15;
  int wm = (wave >> 1) * 64, wn = (wave & 1) * 64;
  const short* Ab = A + (size_t)m0 * 1024;
  const short* Bb = Bt + (size_t)n0 * 1024;
  int srow = t >> 2, lk = (t & 3) * 8;

  gl_lds16(Ab + (size_t)srow * 1024 + lk, Ls + t * 8);
  gl_lds16(Ab + (size_t)(srow + 64) * 1024 + lk, Ls + 2048 + t * 8);
  gl_lds16(Bb + (size_t)srow * 1024 + lk, Ls + 4096 + t * 8);
  gl_lds16(Bb + (size_t)(srow + 64) * 1024 + lk, Ls + 4096 + 2048 + t * 8);
  gl_lds16(Ab + (size_t)srow * 1024 + 32 + lk, Ls + 8192 + t * 8);
  gl_lds16(Ab + (size_t)(srow + 64) * 1024 + 32 + lk, Ls + 8192 + 2048 + t * 8);
  gl_lds16(Bb + (size_t)srow * 1024 + 32 + lk, Ls + 8192 + 4096 + t * 8);
  gl_lds16(Bb + (size_t)(srow + 64) * 1024 + 32 + lk,
           Ls + 8192 + 4096 + 2048 + t * 8);

  for (int g = 0; g < 10; g++) {
    int kb = g * 96;
    gstep<0, 0>(Ab, Bb, Ls, kb + 64, t, srow, lk, wm, wn, col, quad, acc);
    gstep<1, 0>(Ab, Bb, Ls, kb + 96, t, srow, lk, wm, wn, col, quad, acc);
    gstep<2, 0>(Ab, Bb, Ls, kb + 128, t, srow, lk, wm, wn, col, quad, acc);
  }
  gstep<0, 1>(Ab, Bb, Ls, 0, t, srow, lk, wm, wn, col, quad, acc);
  gstep<1, 2>(Ab, Bb, Ls, 0, t, srow, lk, wm, wn, col, quad, acc);
}

// GEMM1. Grid (24, nb*8). Q pre-scaled by 0.125 (exact).
// R19: blocks whose entire 128-row range is masked (mloc >= len) return
// immediately -- attn provably never reads those Qb/Kb/VTb regions.
__global__ __launch_bounds__(256, 3) void gemm_qkv_k(
    const short* __restrict__ xbf, const short* __restrict__ wT,
    const char* __restrict__ bias, short* __restrict__ Qb,
    short* __restrict__ Kb, short* __restrict__ VTb,
    const int* __restrict__ flag, const int* __restrict__ lengths,
    int b_base) {
  __shared__ __align__(16) short Ls[3 * 8192];
  int m0 = blockIdx.y * 128, n0 = blockIdx.x * 128;
  int bll = m0 >> 10;  // batch index local to buffer
  int len = lengths[b_base + bll];
  int mloc = m0 & 1023;
  if (mloc >= len) return;  // block-uniform, before any barrier

  int isf32 = *flag;
  f32x4 acc[4][4];
#pragma unroll
  for (int i = 0; i < 4; i++)
#pragma unroll
    for (int j = 0; j < 4; j++) acc[i][j] = f32x4{0.f, 0.f, 0.f, 0.f};
  gemm_core(xbf, wT, Ls, m0, n0, acc);
  int t = threadIdx.x, wave = t >> 6, lane = t & 63, quad = lane >> 4,
      col = lane & 15;
  int wm = (wave >> 1) * 64, wn = (wave & 1) * 64;
#pragma unroll
  for (int j = 0; j < 4; j++) {
    int n = n0 + wn + j * 16 + col;
    float bv = ldbias(bias, n, isf32);
    int qi = n >> 10, d = n & 1023, h = d >> 6, dh = d & 63;
#pragma unroll
    for (int i = 0; i < 4; i++) {
#pragma unroll
      for (int r = 0; r < 4; r++) {
        int m = m0 + wm + i * 16 + quad * 4 + r;
        int bl = m >> 10, tp = m & 1023;
        size_t bh = (size_t)bl * 16 + h;
        float val = acc[i][j][r] + bv;
        if (qi == 0)
          Qb[(bh * 1024 + tp) * 64 + dh] = f2b(val * 0.125f);
        else if (qi == 1)
          Kb[(bh * 1024 + tp) * 64 + dh] = f2b(val);
        else
          VTb[(bh * 64 + dh) * 1024 + tp] = f2b(val);
      }
    }
  }
}

// attention. Grid (8, nb*16), 4 waves; each wave owns 32 q-rows (2 q-tiles).
// R18 structure: K LDS-staged distance-1 dbuf, one __syncthreads per tile,
// V via T14 register prefetch, wave-private P round-trip, early-exit.
__global__ __launch_bounds__(256, 4) void attn_k(
    const short* __restrict__ Qb, const short* __restrict__ Kb,
    const short* __restrict__ VTb, const int* __restrict__ lengths,
    short* __restrict__ Ob, int b_base) {
  __shared__ __align__(16) short Ks[2][2][64 * 32];  // [buf][half][key][d]
  __shared__ __align__(16) short Pl[4 * 32 * 72];
  int t = threadIdx.x, wave = t >> 6, lane = t & 63, quad = lane >> 4,
      col = lane & 15;
  int bh = blockIdx.y, bl = bh >> 4, h = bh & 15;
  int len = lengths[b_base + bl];
  int qblk = blockIdx.x * 128;
  if (qblk >= len) {
    bf16x8 z;
#pragma unroll
    for (int j = 0; j < 8; j++) z[j] = 0;
    int rr = t >> 1, cc = (t & 1) * 32;
    short* dst = Ob + ((size_t)bl * 1024 + qblk + rr) * 1024 + h * 64 + cc;
#pragma unroll
    for (int j = 0; j < 4; j++) *(bf16x8*)(dst + j * 8) = z;
    return;
  }
  int qb0 = qblk + wave * 16;  // qt adds +64
  const short* Q = Qb + (size_t)bh * 1024 * 64;
  const short* K = Kb + (size_t)bh * 1024 * 64;
  const short* VT = VTb + (size_t)bh * 64 * 1024;
  short* myP = Pl + wave * 32 * 72;

  int srow = t >> 2, skk = (t & 3) * 8;

  bf16x8 qf[2][2];
#pragma unroll
  for (int qt = 0; qt < 2; qt++) {
    qf[qt][0] = *(const bf16x8*)(Q + (qb0 + qt * 64 + col) * 64 + quad * 8);
    qf[qt][1] =
        *(const bf16x8*)(Q + (qb0 + qt * 64 + col) * 64 + 32 + quad * 8);
  }

  f32x4 oacc[2][4];
  float suml[2][4];
#pragma unroll
  for (int qt = 0; qt < 2; qt++)
#pragma unroll
    for (int i = 0; i < 4; i++) {
      oacc[qt][i] = f32x4{0.f, 0.f, 0.f, 0.f};
      suml[qt][i] = 0.f;
    }

  int klim = ((len + 63) >> 6) << 6;  // block-uniform, <= 1024

  gl_lds16(K + (size_t)srow * 64 + skk, Ks[0][0] + t * 8);
  gl_lds16(K + (size_t)srow * 64 + 32 + skk, Ks[0][1] + t * 8);
  __syncthreads();

  for (int k0 = 0; k0 < klim; k0 += 64) {
    int cur = (k0 >> 6) & 1;
    if (k0 + 64 < klim) {
      int nx = cur ^ 1, kn = k0 + 64;
      gl_lds16(K + (size_t)(kn + srow) * 64 + skk, Ks[nx][0] + t * 8);
      gl_lds16(K + (size_t)(kn + srow) * 64 + 32 + skk, Ks[nx][1] + t * 8);
    }

    // T14: issue V loads for nt=0,1 now; consumed after QK (~600cy cover).
    bf16x8 vr[4][2];
#pragma unroll
    for (int nt = 0; nt < 2; nt++) {
      vr[nt][0] = *(const bf16x8*)(VT + (size_t)(nt * 16 + col) * 1024 + k0 +
                                   quad * 8);
      vr[nt][1] = *(const bf16x8*)(VT + (size_t)(nt * 16 + col) * 1024 + k0 +
                                   32 + quad * 8);
    }

#pragma unroll
    for (int qt = 0; qt < 2; qt++) {
      f32x4 s[4];
#pragma unroll
      for (int ks = 0; ks < 4; ks++) s[ks] = f32x4{0.f, 0.f, 0.f, 0.f};
      __builtin_amdgcn_s_setprio(1);
#pragma unroll
      for (int ks = 0; ks < 4; ks++) {
        bf16x8 klo =
            *(const bf16x8*)(Ks[cur][0] + (ks * 16 + col) * 32 + quad * 8);
        bf16x8 khi =
            *(const bf16x8*)(Ks[cur][1] + (ks * 16 + col) * 32 + quad * 8);
        s[ks] = __builtin_amdgcn_mfma_f32_16x16x32_bf16(qf[qt][0], klo, s[ks],
                                                        0, 0, 0);
        s[ks] = __builtin_amdgcn_mfma_f32_16x16x32_bf16(qf[qt][1], khi, s[ks],
                                                        0, 0, 0);
      }
      __builtin_amdgcn_s_setprio(0);
#pragma unroll
      for (int ks = 0; ks < 4; ks++) {
#pragma unroll
        for (int r = 0; r < 4; r++) {
          float e = (k0 + ks * 16 + col < len) ? __expf(s[ks][r]) : 0.f;
          suml[qt][r] += e;
          myP[(qt * 16 + quad * 4 + r) * 72 + ks * 16 + col] = f2b(e);
        }
      }
    }

    // T14: issue V loads for nt=2,3; consumed after the P round-trip.
#pragma unroll
    for (int nt = 2; nt < 4; nt++) {
      vr[nt][0] = *(const bf16x8*)(VT + (size_t)(nt * 16 + col) * 1024 + k0 +
                                   quad * 8);
      vr[nt][1] = *(const bf16x8*)(VT + (size_t)(nt * 16 + col) * 1024 + k0 +
                                   32 + quad * 8);
    }

#pragma unroll
    for (int qt = 0; qt < 2; qt++) {
      bf16x8 pf0 = *(const bf16x8*)(myP + (qt * 16 + col) * 72 + quad * 8);
      bf16x8 pf1 = *(const bf16x8*)(myP + (qt * 16 + col) * 72 + 32 + quad * 8);
      __builtin_amdgcn_s_setprio(1);
#pragma unroll
      for (int nt = 0; nt < 4; nt++) {
        oacc[qt][nt] = __builtin_amdgcn_mfma_f32_16x16x32_bf16(
            pf0, vr[nt][0], oacc[qt][nt], 0, 0, 0);
        oacc[qt][nt] = __builtin_amdgcn_mfma_f32_16x16x32_bf16(
            pf1, vr[nt][1], oacc[qt][nt], 0, 0, 0);
      }
      __builtin_amdgcn_s_setprio(0);
    }
    __syncthreads();
  }
#pragma unroll
  for (int qt = 0; qt < 2; qt++)
#pragma unroll
    for (int r = 0; r < 4; r++) {
      suml[qt][r] += __shfl_xor(suml[qt][r], 1);
      suml[qt][r] += __shfl_xor(suml[qt][r], 2);
      suml[qt][r] += __shfl_xor(suml[qt][r], 4);
      suml[qt][r] += __shfl_xor(suml[qt][r], 8);
    }
#pragma unroll
  for (int qt = 0; qt < 2; qt++)
#pragma unroll
    for (int nt = 0; nt < 4; nt++)
#pragma unroll
      for (int r = 0; r < 4; r++) {
        int q = qb0 + qt * 64 + quad * 4 + r;
        float v = (q < len) ? oacc[qt][nt][r] / suml[qt][r] : 0.f;
        Ob[((size_t)bl * 1024 + q) * 1024 + h * 64 + nt * 16 + col] = f2b(v);
      }
}

// GEMM2. Grid (8, nb*8). Output dtype follows flag.
// R19: blocks fully masked (mloc >= len) write the bias broadcast (reference
// value for masked rows: 0 @ w_o + b_o = b_o) and skip the GEMM.
__global__ __launch_bounds__(256, 3) void gemm_out_k(
    const short* __restrict__ O, const short* __restrict__ wT,
    const char* __restrict__ bias, char* __restrict__ out,
    const int* __restrict__ flag, int m_base,
    const int* __restrict__ lengths) {
  __shared__ __align__(16) short Ls[3 * 8192];
  int isf32 = *flag;
  int m0 = blockIdx.y * 128, n0 = blockIdx.x * 128;
  int gm = m_base + m0;
  int len = lengths[gm >> 10];
  int mloc = gm & 1023;
  if (mloc >= len) {
    // out rows = b_o broadcast. Lane = n-column (coalesced per row).
    int t = threadIdx.x;
    int nn = n0 + (t & 127);
    float bv = ldbias(bias, nn, isf32);
    int mstart = m0 + (t >> 7) * 64;
    for (int j = 0; j < 64; j++) {
      size_t idx = (size_t)(m_base + mstart + j) * 1024 + nn;
      if (isf32)
        ((float*)out)[idx] = bv;
      else
        ((short*)out)[idx] = f2b(bv);
    }
    return;
  }
  f32x4 acc[4][4];
#pragma unroll
  for (int i = 0; i < 4; i++)
#pragma unroll
    for (int j = 0; j < 4; j++) acc[i][j] = f32x4{0.f, 0.f, 0.f, 0.f};
  gemm_core(O, wT, Ls, m0, n0, acc);
  int t = threadIdx.x, wave = t >> 6, lane = t & 63, quad = lane >> 4,
      col = lane & 15;
  int wm = (wave >> 1) * 64, wn = (wave & 1) * 64;
#pragma unroll
  for (int j = 0; j < 4; j++) {
    int n = n0 + wn + j * 16 + col;
    float bv = ldbias(bias, n, isf32);
#pragma unroll
    for (int i = 0; i < 4; i++) {
#pragma unroll
      for (int r = 0; r < 4; r++) {
        int m = m0 + wm + i * 16 + quad * 4 + r;
        size_t idx = (size_t)(m_base + m) * 1024 + n;
        float val = acc[i][j][r] + bv;
        if (isf32)
          ((float*)out)[idx] = val;
        else
          ((short*)out)[idx] = f2b(val);
      }
    }
  }
}

extern "C" void kernel_launch(void* const* d_in, const int* in_sizes, int n_in,
                              void* d_out, int out_size, void* d_ws,
                              size_t ws_size, hipStream_t stream) {
  const char* x = (const char*)d_in[0];
  const int* lengths = (const int*)d_in[1];
  const char* w_qkv = (const char*)d_in[2];
  const char* b_qkv = (const char*)d_in[3];
  const char* w_o = (const char*)d_in[4];
  const char* b_o = (const char*)d_in[5];
  char* out = (char*)d_out;

  char* ws = (char*)d_ws;
  int* flag = (int*)ws;        ws += 256;
  short* wT_qkv = (short*)ws;  ws += (size_t)3072 * 1024 * 2;  // 6.3 MB
  short* wT_o = (short*)ws;    ws += (size_t)1024 * 1024 * 2;  // 2.1 MB
  char* dynbase = ws;
  size_t fixed = (size_t)(dynbase - (char*)d_ws);
  size_t per_batch = (size_t)16 * 1024 * 64 * 2;  // 2.10 MB / tensor
  size_t need_full = fixed + 4 * 8 * per_batch;   // ~75.8 MB (fits, R3-R5)
  int nb = (ws_size >= need_full) ? 8 : 1;

  // xbf aliases Ob: x consumed by GEMM1 before attn writes Ob.
  short* xbf_Ob = (short*)dynbase;
  short* Qb = xbf_Ob + (size_t)nb * 16 * 1024 * 64;
  short* Kb = Qb + (size_t)nb * 16 * 1024 * 64;
  short* VTb = Kb + (size_t)nb * 16 * 1024 * 64;

  dim3 blk(256);
  probe_k<<<1, 64, 0, stream>>>((const short*)x, flag);
  transpose_k<<<dim3(48, 16), blk, 0, stream>>>(w_qkv, wT_qkv, 1024, 3072, flag);
  transpose_k<<<dim3(16, 16), blk, 0, stream>>>(w_o, wT_o, 1024, 1024, flag);
  for (int b0 = 0; b0 < 8; b0 += nb) {
    cvt_x_k<<<dim3(nb * 512), blk, 0, stream>>>(x, xbf_Ob, flag, b0);
    gemm_qkv_k<<<dim3(24, nb * 8), blk, 0, stream>>>(xbf_Ob, wT_qkv, b_qkv, Qb,
                                                     Kb, VTb, flag, lengths,
                                                     b0);
    attn_k<<<dim3(8, nb * 16), blk, 0, stream>>>(Qb, Kb, VTb, lengths, xbf_Ob,
                                                 b0);
    gemm_out_k<<<dim3(8, nb * 8), blk, 0, stream>>>(xbf_Ob, wT_o, b_o, out,
                                                    flag, b0 * 1024, lengths);
  }
}